// Round 12
// baseline (310.680 us; speedup 1.0000x reference)
//
#include <hip/hip_runtime.h>
#include <hip/hip_bf16.h>
#include <math.h>

#define N_TOK 4096
#define D_IN  768
#define N_EXP 8
#define NP    8192      // N_TOK * TOPK
#define H_DIM 3072
#define BM    128
#define BK    64
#define BK1   32
#define BN1   128
#define BN2   128
#define MAXT  72
#define GRID1 (MAXT * (H_DIM / BN1))   // 1728, div by 8
#define GRID2 (MAXT * (D_IN / BN2))    // 432, div by 8
#define NT_BLKS 3456                   // 24 mats * 144 tiles (64 rows x 256 cols)
#define TPE   144

typedef float f32x4 __attribute__((ext_vector_type(4)));
typedef short s16x8 __attribute__((ext_vector_type(8)));

__device__ __forceinline__ unsigned short f2bf(float f) {
    unsigned int u = __builtin_bit_cast(unsigned int, f);
    u += 0x7fffu + ((u >> 16) & 1u);
    return (unsigned short)(u >> 16);
}

__device__ __forceinline__ void gload_lds16(const void* g, void* l) {
    __builtin_amdgcn_global_load_lds(
        (const __attribute__((address_space(1))) unsigned int*)g,
        (__attribute__((address_space(3))) unsigned int*)l, 16, 0, 0);
}

__device__ __forceinline__ int xcd_swz(int bid, int nblk) {
    int chunk = nblk >> 3;
    return (bid & 7) * chunk + (bid >> 3);
}

__device__ __forceinline__ bool tile_map(const int* counts, int bx, int& e, int& g0, int& vr) {
    int off = 0, nt = 0;
    e = -1;
    int lb = 0, cnt = 0;
#pragma unroll
    for (int ee = 0; ee < N_EXP; ee++) {
        int c = counts[ee];
        int t = (c + BM - 1) >> 7;
        if (bx >= nt && bx < nt + t) { e = ee; lb = (bx - nt) * BM; g0 = off + lb; cnt = c; }
        nt += t; off += c;
    }
    if (e < 0) return false;
    vr = cnt - lb; if (vr > BM) vr = BM;
    return true;
}

// ---- transpose: register-only, 64x256 per block, 2 independent chains/thread ----
__global__ __launch_bounds__(256) void transpose_kernel(
    const float* __restrict__ w1, const float* __restrict__ w2, const float* __restrict__ w3,
    unsigned short* __restrict__ W1T, unsigned short* __restrict__ W2T,
    unsigned short* __restrict__ W3T) {
    int bid = blockIdx.x, tid = threadIdx.x;
    int z = bid / TPE;
    int tt = bid - z * TPE;
    const float* s;
    unsigned short* d;
    int R, C, tc;
    if (z < 8)       { s = w1 + (size_t)z * D_IN * H_DIM;        d = W1T + (size_t)z * H_DIM * D_IN;        R = D_IN;  C = H_DIM; tc = 12; }
    else if (z < 16) { s = w2 + (size_t)(z - 8) * D_IN * H_DIM;  d = W2T + (size_t)(z - 8) * H_DIM * D_IN;  R = D_IN;  C = H_DIM; tc = 12; }
    else             { s = w3 + (size_t)(z - 16) * H_DIM * D_IN; d = W3T + (size_t)(z - 16) * D_IN * H_DIM; R = H_DIM; C = D_IN;  tc = 3;  }
    int r0 = (tt / tc) * 64, c0 = (tt % tc) * 256;
    int lane = tid & 63, w = tid >> 6;
    int tx = lane & 7, ty = lane >> 3;
    int cb = c0 + 32 * w + 4 * tx;
    int rb2 = r0 + 8 * ty;
    const float* sp  = s + (size_t)rb2 * C + cb;
    const float* sp2 = sp + 128;
    f32x4 L[8], M[8];
#pragma unroll
    for (int i = 0; i < 8; i++)
        L[i] = __builtin_nontemporal_load((const f32x4*)(sp + (size_t)i * C));
#pragma unroll
    for (int i = 0; i < 8; i++)
        M[i] = __builtin_nontemporal_load((const f32x4*)(sp2 + (size_t)i * C));
#pragma unroll
    for (int j = 0; j < 4; j++) {
        s16x8 o;
#pragma unroll
        for (int k = 0; k < 8; k++) o[k] = (short)f2bf(L[k][j]);
        *(s16x8*)&d[(size_t)(cb + j) * R + rb2] = o;
    }
#pragma unroll
    for (int j = 0; j < 4; j++) {
        s16x8 o;
#pragma unroll
        for (int k = 0; k < 8; k++) o[k] = (short)f2bf(M[k][j]);
        *(s16x8*)&d[(size_t)(cb + 128 + j) * R + rb2] = o;
    }
}

// ---- router: 256 blocks x 256 thr; 16 lanes per token (48 dims each), shfl reduce ----
__global__ __launch_bounds__(256) void router_kernel(
    const float* __restrict__ x, const float* __restrict__ rw, const float* __restrict__ rb,
    int* counts, int* top1cnt, float* probs_sum, int* tk_e, float* tk_w) {
    __shared__ float s_ps[N_EXP];
    __shared__ int s_cnt[N_EXP], s_t1[N_EXP];
    int tid = threadIdx.x;
    if (tid < N_EXP) { s_ps[tid] = 0.f; s_cnt[tid] = 0; s_t1[tid] = 0; }
    __syncthreads();
    int tok = blockIdx.x * 16 + (tid >> 4);
    int part = tid & 15;           // 48 dims each
    float acc[N_EXP];
#pragma unroll
    for (int e = 0; e < N_EXP; e++) acc[e] = 0.f;
    const float* xr = x + (size_t)tok * D_IN + part * 48;
    const float* rwr = rw + (size_t)part * 48 * N_EXP;
    for (int dd = 0; dd < 48; dd++) {
        float xv = xr[dd];
        f32x4 ra = *(const f32x4*)(rwr + dd * N_EXP);
        f32x4 rbv = *(const f32x4*)(rwr + dd * N_EXP + 4);
        acc[0] += xv * ra[0]; acc[1] += xv * ra[1]; acc[2] += xv * ra[2]; acc[3] += xv * ra[3];
        acc[4] += xv * rbv[0]; acc[5] += xv * rbv[1]; acc[6] += xv * rbv[2]; acc[7] += xv * rbv[3];
    }
#pragma unroll
    for (int s = 1; s < 16; s <<= 1)
#pragma unroll
        for (int e = 0; e < N_EXP; e++) acc[e] += __shfl_xor(acc[e], s, 64);
    if (part == 0) {
        float p[N_EXP], m, ssum = 0.f;
#pragma unroll
        for (int e = 0; e < N_EXP; e++) acc[e] += rb[e];
        m = acc[0];
#pragma unroll
        for (int e = 1; e < N_EXP; e++) m = fmaxf(m, acc[e]);
#pragma unroll
        for (int e = 0; e < N_EXP; e++) { p[e] = __expf(acc[e] - m); ssum += p[e]; }
        float inv = 1.f / ssum;
#pragma unroll
        for (int e = 0; e < N_EXP; e++) p[e] *= inv;
        int e0 = 0;
#pragma unroll
        for (int e = 1; e < N_EXP; e++) if (p[e] > p[e0]) e0 = e;
        int e1 = (e0 == 0) ? 1 : 0;
#pragma unroll
        for (int e = 0; e < N_EXP; e++) if (e != e0 && p[e] > p[e1]) e1 = e;
        float denom = 1.f / (p[e0] + p[e1]);
        tk_e[tok * 2] = e0; tk_e[tok * 2 + 1] = e1;
        tk_w[tok * 2] = p[e0] * denom; tk_w[tok * 2 + 1] = p[e1] * denom;
        atomicAdd(&s_cnt[e0], 1); atomicAdd(&s_cnt[e1], 1); atomicAdd(&s_t1[e0], 1);
#pragma unroll
        for (int e = 0; e < N_EXP; e++) atomicAdd(&s_ps[e], p[e]);
    }
    __syncthreads();
    if (tid < N_EXP) {
        atomicAdd(&counts[tid], s_cnt[tid]);
        atomicAdd(&top1cnt[tid], s_t1[tid]);
        atomicAdd(&probs_sum[tid], s_ps[tid]);
    }
}

// ---- scatter: permutation via inline prefix of counts; block0 computes aux ----
__global__ __launch_bounds__(64) void scatter_kernel(
    const int* __restrict__ tk_e, const float* __restrict__ tk_w,
    const int* __restrict__ counts, int* cursors,
    int* rowTok, float* rowGate, int* pairPos,
    const int* __restrict__ top1cnt, const float* __restrict__ probs_sum, float* aux_out) {
    int tid = threadIdx.x;
    int tok = blockIdx.x * 64 + tid;
    int segOff[N_EXP];
    int off = 0;
#pragma unroll
    for (int e = 0; e < N_EXP; e++) { segOff[e] = off; off += counts[e]; }
#pragma unroll
    for (int k = 0; k < 2; k++) {
        int e = tk_e[tok * 2 + k];
        int pos = segOff[e] + atomicAdd(&cursors[e], 1);
        rowTok[pos] = tok;
        rowGate[pos] = tk_w[tok * 2 + k];
        pairPos[tok * 2 + k] = pos;
    }
    if (blockIdx.x == 0 && tid == 0) {
        float aux = 0.f;
#pragma unroll
        for (int e = 0; e < N_EXP; e++) aux += (float)top1cnt[e] * probs_sum[e];
        aux_out[0] = (float)N_EXP * aux / ((float)N_TOK * (float)N_TOK);
    }
}

// ---- gather ----
__global__ __launch_bounds__(192) void gather_kernel(
    const float* __restrict__ x, const int* __restrict__ rowTok, unsigned short* __restrict__ Xg) {
    int pos = blockIdx.x;
    int t = rowTok[pos];
    int i = threadIdx.x;
    float4 v = ((const float4*)(x + (size_t)t * D_IN))[i];
    unsigned long long pk = (unsigned long long)f2bf(v.x)
                          | ((unsigned long long)f2bf(v.y) << 16)
                          | ((unsigned long long)f2bf(v.z) << 32)
                          | ((unsigned long long)f2bf(v.w) << 48);
    *(unsigned long long*)(Xg + (size_t)pos * D_IN + (size_t)i * 4) = pk;
}

// ---- ffn1: H = silu(X@W1+b1) * (X@W2+b2), bf16 out ----
// BK1=32 counted-vmcnt double-buffer: 24 KB/buffer (48 KB total, 3 blocks/CU),
// 3 loads/thread/K-step, steady-state vmcnt(3) keeps next tile in flight.
// 64B rows: swizzle c ^= (row>>1)&3 (banks spread over all 8 groups, 2-way free).
__global__ __launch_bounds__(512) void ffn1_kernel(
    const unsigned short* __restrict__ Xg, const unsigned short* __restrict__ W1T,
    const unsigned short* __restrict__ W2T, const float* __restrict__ b1,
    const float* __restrict__ b2, unsigned short* __restrict__ Hbuf,
    const int* __restrict__ counts) {
    int u = xcd_swz(blockIdx.x, GRID1);
    int bx = u / (H_DIM / BN1);
    int by = u - bx * (H_DIM / BN1);
    int e, g0, vr;
    if (!tile_map(counts, bx, e, g0, vr)) return;
    int n0 = by * BN1;

    __shared__ __align__(16) unsigned short sA[2][BM * BK1];    // 2 x 8 KB
    __shared__ __align__(16) unsigned short sB1[2][BN1 * BK1];  // 2 x 8 KB
    __shared__ __align__(16) unsigned short sB2[2][BN1 * BK1];  // 2 x 8 KB

    int tid = threadIdx.x, lane = tid & 63, w = tid >> 6;
    int wm = w >> 2, wn = w & 3;
    int lr = lane & 15, lh = lane >> 4;

    f32x4 acc1[4][2], acc2[4][2];
#pragma unroll
    for (int a = 0; a < 4; a++)
#pragma unroll
        for (int b = 0; b < 2; b++) { acc1[a][b] = (f32x4)0.f; acc2[a][b] = (f32x4)0.f; }

    const unsigned short* W1e = W1T + (size_t)e * H_DIM * D_IN;
    const unsigned short* W2e = W2T + (size_t)e * H_DIM * D_IN;

    auto stage = [&](int buf, int kt) {
        int kb = kt * BK1;
        int o = tid * 16;
        int row = o >> 6;                         // 64B rows
        int c = ((o >> 4) & 3) ^ ((row >> 1) & 3);
        int gr = g0 + row; if (gr > NP - 1) gr = NP - 1;
        gload_lds16(Xg + (size_t)gr * D_IN + kb + c * 8, (char*)&sA[buf][0] + o);
        size_t src = (size_t)(n0 + row) * D_IN + kb + c * 8;
        gload_lds16(W1e + src, (char*)&sB1[buf][0] + o);
        gload_lds16(W2e + src, (char*)&sB2[buf][0] + o);
    };

    const int NKT = D_IN / BK1; // 24
    stage(0, 0);
    stage(1, 1);
    __builtin_amdgcn_sched_barrier(0);
#pragma unroll 1
    for (int kt = 0; kt < NKT; ++kt) {
        if (kt < NKT - 1) { asm volatile("s_waitcnt vmcnt(3)" ::: "memory"); }
        else              { asm volatile("s_waitcnt vmcnt(0)" ::: "memory"); }
        __builtin_amdgcn_s_barrier();
        __builtin_amdgcn_sched_barrier(0);
        int cur = kt & 1;
        s16x8 av[4];
#pragma unroll
        for (int mf = 0; mf < 4; ++mf) {
            int r = wm * 64 + mf * 16 + lr;
            av[mf] = *(const s16x8*)&sA[cur][r * 32 + ((lh ^ ((r >> 1) & 3)) << 3)];
        }
#pragma unroll
        for (int nf = 0; nf < 2; ++nf) {
            int n = wn * 32 + nf * 16 + lr;
            int off = n * 32 + ((lh ^ ((n >> 1) & 3)) << 3);
            s16x8 bv1 = *(const s16x8*)&sB1[cur][off];
            s16x8 bv2 = *(const s16x8*)&sB2[cur][off];
#pragma unroll
            for (int mf = 0; mf < 4; ++mf) {
                acc1[mf][nf] = __builtin_amdgcn_mfma_f32_16x16x32_bf16(av[mf], bv1, acc1[mf][nf], 0, 0, 0);
                acc2[mf][nf] = __builtin_amdgcn_mfma_f32_16x16x32_bf16(av[mf], bv2, acc2[mf][nf], 0, 0, 0);
            }
        }
        __builtin_amdgcn_sched_barrier(0);
        __builtin_amdgcn_s_barrier();
        if (kt + 2 < NKT) { stage(cur, kt + 2); __builtin_amdgcn_sched_barrier(0); }
    }
#pragma unroll
    for (int mf = 0; mf < 4; ++mf) {
        int rbase = wm * 64 + mf * 16 + lh * 4;
#pragma unroll
        for (int nf = 0; nf < 2; ++nf) {
            int n = n0 + wn * 32 + nf * 16 + lr;
            float bb1 = b1[e * H_DIM + n], bb2 = b2[e * H_DIM + n];
#pragma unroll
            for (int j = 0; j < 4; ++j) {
                int r = rbase + j;
                if (r < vr) {
                    float x1 = acc1[mf][nf][j] + bb1;
                    float x2 = acc2[mf][nf][j] + bb2;
                    float h = x1 / (1.f + __expf(-x1)) * x2;
                    Hbuf[(size_t)(g0 + r) * H_DIM + n] = f2bf(h);
                }
            }
        }
    }
}

// ---- ffn2: Y = gate * (H@W3 + b3), f32 out (R8 structure) ----
__global__ __launch_bounds__(256) void ffn2_kernel(
    const unsigned short* __restrict__ Hbuf, const unsigned short* __restrict__ W3T,
    const float* __restrict__ b3, const float* __restrict__ rowGate,
    float* __restrict__ Ybuf, const int* __restrict__ counts) {
    int u = xcd_swz(blockIdx.x, GRID2);
    int bx = u / (D_IN / BN2);
    int by = u - bx * (D_IN / BN2);
    int e, g0, vr;
    if (!tile_map(counts, bx, e, g0, vr)) return;
    int n0 = by * BN2;

    __shared__ __align__(16) unsigned short sA[2][BM * BK];
    __shared__ __align__(16) unsigned short sB[2][BN2 * BK];

    int tid = threadIdx.x, lane = tid & 63, w = tid >> 6;
    int wm = w >> 1, wn = w & 1;
    int lr = lane & 15, lh = lane >> 4;

    f32x4 acc[4][4];
#pragma unroll
    for (int a = 0; a < 4; a++)
#pragma unroll
        for (int b = 0; b < 4; b++) acc[a][b] = (f32x4)0.f;

    const unsigned short* W3e = W3T + (size_t)e * D_IN * H_DIM;

    auto stage = [&](int buf, int kt) {
        int kb = kt * BK;
#pragma unroll
        for (int ca = 0; ca < 4; ca++) {
            int o = ca * 4096 + tid * 16;
            int row = o >> 7;
            int c = ((o >> 4) & 7) ^ (row & 7);
            int gr = g0 + row; if (gr > NP - 1) gr = NP - 1;
            gload_lds16(Hbuf + (size_t)gr * H_DIM + kb + c * 8, (char*)&sA[buf][0] + o);
        }
#pragma unroll
        for (int cb = 0; cb < 4; cb++) {
            int o = cb * 4096 + tid * 16;
            int row = o >> 7;
            int c = ((o >> 4) & 7) ^ (row & 7);
            gload_lds16(W3e + (size_t)(n0 + row) * H_DIM + kb + c * 8, (char*)&sB[buf][0] + o);
        }
    };

    const int NKT = H_DIM / BK;
    stage(0, 0);
    stage(1, 1);
    __builtin_amdgcn_sched_barrier(0);
#pragma unroll 1
    for (int kt = 0; kt < NKT; ++kt) {
        if (kt < NKT - 1) { asm volatile("s_waitcnt vmcnt(8)" ::: "memory"); }
        else              { asm volatile("s_waitcnt vmcnt(0)" ::: "memory"); }
        __builtin_amdgcn_s_barrier();
        __builtin_amdgcn_sched_barrier(0);
        int cur = kt & 1;
#pragma unroll
        for (int ks = 0; ks < 2; ++ks) {
            int sb = ks * 4 + lh;
            s16x8 av[4], bv[4];
#pragma unroll
            for (int mf = 0; mf < 4; ++mf) {
                int r = wm * 64 + mf * 16 + lr;
                av[mf] = *(const s16x8*)&sA[cur][r * 64 + ((sb ^ (r & 7)) << 3)];
            }
#pragma unroll
            for (int nf = 0; nf < 4; ++nf) {
                int n = wn * 64 + nf * 16 + lr;
                bv[nf] = *(const s16x8*)&sB[cur][n * 64 + ((sb ^ (n & 7)) << 3)];
            }
#pragma unroll
            for (int nf = 0; nf < 4; ++nf)
#pragma unroll
                for (int mf = 0; mf < 4; ++mf)
                    acc[mf][nf] = __builtin_amdgcn_mfma_f32_16x16x32_bf16(av[mf], bv[nf], acc[mf][nf], 0, 0, 0);
        }
        __builtin_amdgcn_sched_barrier(0);
        __builtin_amdgcn_s_barrier();
        if (kt + 2 < NKT) { stage(cur, kt + 2); __builtin_amdgcn_sched_barrier(0); }
    }
#pragma unroll
    for (int mf = 0; mf < 4; ++mf) {
        int rbase = wm * 64 + mf * 16 + lh * 4;
#pragma unroll
        for (int nf = 0; nf < 4; ++nf) {
            int n = n0 + wn * 64 + nf * 16 + lr;
            float bb = b3[e * D_IN + n];
#pragma unroll
            for (int j = 0; j < 4; ++j) {
                int r = rbase + j;
                if (r < vr) {
                    float g = rowGate[g0 + r];
                    Ybuf[(size_t)(g0 + r) * D_IN + n] = g * (acc[mf][nf][j] + bb);
                }
            }
        }
    }
}

// ---- combine ----
__global__ __launch_bounds__(192) void combine_kernel(
    const float* __restrict__ Ybuf, const int* __restrict__ pairPos, float* __restrict__ out) {
    int t = blockIdx.x, i = threadIdx.x;
    int p0 = pairPos[t * 2], p1 = pairPos[t * 2 + 1];
    float4 a = ((const float4*)(Ybuf + (size_t)p0 * D_IN))[i];
    float4 b = ((const float4*)(Ybuf + (size_t)p1 * D_IN))[i];
    float4 r; r.x = a.x + b.x; r.y = a.y + b.y; r.z = a.z + b.z; r.w = a.w + b.w;
    ((float4*)(out + (size_t)t * D_IN))[i] = r;
}

extern "C" void kernel_launch(void* const* d_in, const int* in_sizes, int n_in,
                              void* d_out, int out_size, void* d_ws, size_t ws_size,
                              hipStream_t stream) {
    const float* x  = (const float*)d_in[0];
    const float* rw = (const float*)d_in[1];
    const float* rb = (const float*)d_in[2];
    const float* w1 = (const float*)d_in[3];
    const float* b1 = (const float*)d_in[4];
    const float* w2 = (const float*)d_in[5];
    const float* b2 = (const float*)d_in[6];
    const float* w3 = (const float*)d_in[7];
    const float* b3 = (const float*)d_in[8];
    float* out = (float*)d_out;

    char* ws = (char*)d_ws;
    const size_t sW = (size_t)N_EXP * H_DIM * D_IN * 2;
    unsigned short* W1T = (unsigned short*)(ws);
    unsigned short* W2T = (unsigned short*)(ws + sW);
    unsigned short* W3T = (unsigned short*)(ws + 2 * sW);
    unsigned short* Xg  = (unsigned short*)(ws + 3 * sW);
    unsigned short* Hb  = (unsigned short*)(ws + 3 * sW + (size_t)NP * D_IN * 2);
    float* Yb = (float*)(ws + 3 * sW + (size_t)NP * D_IN * 2 + (size_t)NP * H_DIM * 2);
    char* meta = (char*)(Yb + (size_t)NP * D_IN);
    int*   counts  = (int*)(meta + 0);
    int*   top1    = (int*)(meta + 32);
    float* psum    = (float*)(meta + 64);
    int*   cursors = (int*)(meta + 96);
    int*   tk_e    = (int*)(meta + 1024);
    float* tk_w    = (float*)(meta + 1024 + 32768);
    int*   rowTok  = (int*)(meta + 1024 + 65536);
    float* rowGate = (float*)(meta + 1024 + 98304);
    int*   pairPos = (int*)(meta + 1024 + 131072);
    size_t need = (size_t)(meta - ws) + 1024 + 163840;
    if (ws_size < need) return;

    hipMemsetAsync(meta, 0, 128, stream);
    router_kernel<<<N_TOK / 16, 256, 0, stream>>>(x, rw, rb, counts, top1, psum, tk_e, tk_w);
    transpose_kernel<<<NT_BLKS, 256, 0, stream>>>(w1, w2, w3, W1T, W2T, W3T);
    scatter_kernel<<<N_TOK / 64, 64, 0, stream>>>(
        tk_e, tk_w, counts, cursors, rowTok, rowGate, pairPos,
        top1, psum, out + (size_t)N_TOK * D_IN);
    gather_kernel<<<NP, 192, 0, stream>>>(x, rowTok, Xg);
    ffn1_kernel<<<GRID1, 512, 0, stream>>>(Xg, W1T, W2T, b1, b2, Hb, counts);
    ffn2_kernel<<<GRID2, 256, 0, stream>>>(Hb, W3T, b3, rowGate, Yb, counts);
    combine_kernel<<<N_TOK, 192, 0, stream>>>(Yb, pairPos, out);
}

// Round 13
// 295.233 us; speedup vs baseline: 1.0523x; 1.0523x over previous
//
#include <hip/hip_runtime.h>
#include <hip/hip_bf16.h>
#include <math.h>

#define N_TOK 4096
#define D_IN  768
#define N_EXP 8
#define NP    8192      // N_TOK * TOPK
#define H_DIM 3072
#define BM    128
#define BK    64
#define BN1   128
#define BN2   128
#define MAXT  72
#define GRID1 (MAXT * (H_DIM / BN1))   // 1728, div by 8
#define GRID2 (MAXT * (D_IN / BN2))    // 432, div by 8
#define NT_BLKS 3456                   // 24 mats * 144 tiles (64 rows x 256 cols)
#define TPE   144

typedef float f32x4 __attribute__((ext_vector_type(4)));
typedef short s16x8 __attribute__((ext_vector_type(8)));

__device__ __forceinline__ unsigned short f2bf(float f) {
    unsigned int u = __builtin_bit_cast(unsigned int, f);
    u += 0x7fffu + ((u >> 16) & 1u);
    return (unsigned short)(u >> 16);
}

__device__ __forceinline__ void gload_lds16(const void* g, void* l) {
    __builtin_amdgcn_global_load_lds(
        (const __attribute__((address_space(1))) unsigned int*)g,
        (__attribute__((address_space(3))) unsigned int*)l, 16, 0, 0);
}

__device__ __forceinline__ int xcd_swz(int bid, int nblk) {
    int chunk = nblk >> 3;
    return (bid & 7) * chunk + (bid >> 3);
}

__device__ __forceinline__ bool tile_map(const int* counts, int bx, int& e, int& g0, int& vr) {
    int off = 0, nt = 0;
    e = -1;
    int lb = 0, cnt = 0;
#pragma unroll
    for (int ee = 0; ee < N_EXP; ee++) {
        int c = counts[ee];
        int t = (c + BM - 1) >> 7;
        if (bx >= nt && bx < nt + t) { e = ee; lb = (bx - nt) * BM; g0 = off + lb; cnt = c; }
        nt += t; off += c;
    }
    if (e < 0) return false;
    vr = cnt - lb; if (vr > BM) vr = BM;
    return true;
}

// ---- transpose: register-only, 64x256 per block, 2 independent chains/thread ----
__global__ __launch_bounds__(256) void transpose_kernel(
    const float* __restrict__ w1, const float* __restrict__ w2, const float* __restrict__ w3,
    unsigned short* __restrict__ W1T, unsigned short* __restrict__ W2T,
    unsigned short* __restrict__ W3T) {
    int bid = blockIdx.x, tid = threadIdx.x;
    int z = bid / TPE;
    int tt = bid - z * TPE;
    const float* s;
    unsigned short* d;
    int R, C, tc;
    if (z < 8)       { s = w1 + (size_t)z * D_IN * H_DIM;        d = W1T + (size_t)z * H_DIM * D_IN;        R = D_IN;  C = H_DIM; tc = 12; }
    else if (z < 16) { s = w2 + (size_t)(z - 8) * D_IN * H_DIM;  d = W2T + (size_t)(z - 8) * H_DIM * D_IN;  R = D_IN;  C = H_DIM; tc = 12; }
    else             { s = w3 + (size_t)(z - 16) * H_DIM * D_IN; d = W3T + (size_t)(z - 16) * D_IN * H_DIM; R = H_DIM; C = D_IN;  tc = 3;  }
    int r0 = (tt / tc) * 64, c0 = (tt % tc) * 256;
    int lane = tid & 63, w = tid >> 6;
    int tx = lane & 7, ty = lane >> 3;
    int cb = c0 + 32 * w + 4 * tx;
    int rb2 = r0 + 8 * ty;
    const float* sp  = s + (size_t)rb2 * C + cb;
    const float* sp2 = sp + 128;
    f32x4 L[8], M[8];
#pragma unroll
    for (int i = 0; i < 8; i++)
        L[i] = __builtin_nontemporal_load((const f32x4*)(sp + (size_t)i * C));
#pragma unroll
    for (int i = 0; i < 8; i++)
        M[i] = __builtin_nontemporal_load((const f32x4*)(sp2 + (size_t)i * C));
#pragma unroll
    for (int j = 0; j < 4; j++) {
        s16x8 o;
#pragma unroll
        for (int k = 0; k < 8; k++) o[k] = (short)f2bf(L[k][j]);
        *(s16x8*)&d[(size_t)(cb + j) * R + rb2] = o;
    }
#pragma unroll
    for (int j = 0; j < 4; j++) {
        s16x8 o;
#pragma unroll
        for (int k = 0; k < 8; k++) o[k] = (short)f2bf(M[k][j]);
        *(s16x8*)&d[(size_t)(cb + 128 + j) * R + rb2] = o;
    }
}

// ---- xcvt: x (f32, token order) -> Xc (bf16, token order); no deps ----
__global__ __launch_bounds__(192) void xcvt_kernel(
    const float* __restrict__ x, unsigned short* __restrict__ Xc) {
    int t = blockIdx.x, i = threadIdx.x;
    float4 v = ((const float4*)(x + (size_t)t * D_IN))[i];
    unsigned long long pk = (unsigned long long)f2bf(v.x)
                          | ((unsigned long long)f2bf(v.y) << 16)
                          | ((unsigned long long)f2bf(v.z) << 32)
                          | ((unsigned long long)f2bf(v.w) << 48);
    *(unsigned long long*)(Xc + (size_t)t * D_IN + (size_t)i * 4) = pk;
}

// ---- router: 256 blocks x 256 thr; 16 lanes per token (48 dims each), shfl reduce ----
__global__ __launch_bounds__(256) void router_kernel(
    const float* __restrict__ x, const float* __restrict__ rw, const float* __restrict__ rb,
    int* counts, int* top1cnt, float* probs_sum, int* tk_e, float* tk_w) {
    __shared__ float s_ps[N_EXP];
    __shared__ int s_cnt[N_EXP], s_t1[N_EXP];
    int tid = threadIdx.x;
    if (tid < N_EXP) { s_ps[tid] = 0.f; s_cnt[tid] = 0; s_t1[tid] = 0; }
    __syncthreads();
    int tok = blockIdx.x * 16 + (tid >> 4);
    int part = tid & 15;           // 48 dims each
    float acc[N_EXP];
#pragma unroll
    for (int e = 0; e < N_EXP; e++) acc[e] = 0.f;
    const float* xr = x + (size_t)tok * D_IN + part * 48;
    const float* rwr = rw + (size_t)part * 48 * N_EXP;
    for (int dd = 0; dd < 48; dd++) {
        float xv = xr[dd];
        f32x4 ra = *(const f32x4*)(rwr + dd * N_EXP);
        f32x4 rbv = *(const f32x4*)(rwr + dd * N_EXP + 4);
        acc[0] += xv * ra[0]; acc[1] += xv * ra[1]; acc[2] += xv * ra[2]; acc[3] += xv * ra[3];
        acc[4] += xv * rbv[0]; acc[5] += xv * rbv[1]; acc[6] += xv * rbv[2]; acc[7] += xv * rbv[3];
    }
#pragma unroll
    for (int s = 1; s < 16; s <<= 1)
#pragma unroll
        for (int e = 0; e < N_EXP; e++) acc[e] += __shfl_xor(acc[e], s, 64);
    if (part == 0) {
        float p[N_EXP], m, ssum = 0.f;
#pragma unroll
        for (int e = 0; e < N_EXP; e++) acc[e] += rb[e];
        m = acc[0];
#pragma unroll
        for (int e = 1; e < N_EXP; e++) m = fmaxf(m, acc[e]);
#pragma unroll
        for (int e = 0; e < N_EXP; e++) { p[e] = __expf(acc[e] - m); ssum += p[e]; }
        float inv = 1.f / ssum;
#pragma unroll
        for (int e = 0; e < N_EXP; e++) p[e] *= inv;
        int e0 = 0;
#pragma unroll
        for (int e = 1; e < N_EXP; e++) if (p[e] > p[e0]) e0 = e;
        int e1 = (e0 == 0) ? 1 : 0;
#pragma unroll
        for (int e = 0; e < N_EXP; e++) if (e != e0 && p[e] > p[e1]) e1 = e;
        float denom = 1.f / (p[e0] + p[e1]);
        tk_e[tok * 2] = e0; tk_e[tok * 2 + 1] = e1;
        tk_w[tok * 2] = p[e0] * denom; tk_w[tok * 2 + 1] = p[e1] * denom;
        atomicAdd(&s_cnt[e0], 1); atomicAdd(&s_cnt[e1], 1); atomicAdd(&s_t1[e0], 1);
#pragma unroll
        for (int e = 0; e < N_EXP; e++) atomicAdd(&s_ps[e], p[e]);
    }
    __syncthreads();
    if (tid < N_EXP) {
        atomicAdd(&counts[tid], s_cnt[tid]);
        atomicAdd(&top1cnt[tid], s_t1[tid]);
        atomicAdd(&probs_sum[tid], s_ps[tid]);
    }
}

// ---- scatter: permutation via inline prefix of counts; block0 computes aux ----
__global__ __launch_bounds__(64) void scatter_kernel(
    const int* __restrict__ tk_e, const float* __restrict__ tk_w,
    const int* __restrict__ counts, int* cursors,
    int* rowTok, float* rowGate, int* pairPos,
    const int* __restrict__ top1cnt, const float* __restrict__ probs_sum, float* aux_out) {
    int tid = threadIdx.x;
    int tok = blockIdx.x * 64 + tid;
    int segOff[N_EXP];
    int off = 0;
#pragma unroll
    for (int e = 0; e < N_EXP; e++) { segOff[e] = off; off += counts[e]; }
#pragma unroll
    for (int k = 0; k < 2; k++) {
        int e = tk_e[tok * 2 + k];
        int pos = segOff[e] + atomicAdd(&cursors[e], 1);
        rowTok[pos] = tok;
        rowGate[pos] = tk_w[tok * 2 + k];
        pairPos[tok * 2 + k] = pos;
    }
    if (blockIdx.x == 0 && tid == 0) {
        float aux = 0.f;
#pragma unroll
        for (int e = 0; e < N_EXP; e++) aux += (float)top1cnt[e] * probs_sum[e];
        aux_out[0] = (float)N_EXP * aux / ((float)N_TOK * (float)N_TOK);
    }
}

// ---- ffn1: H = silu(X@W1+b1) * (X@W2+b2), bf16 out (R11 structure) ----
// A staged via per-lane indirect global source (rowTok): LDS dest stays linear.
__global__ __launch_bounds__(512) void ffn1_kernel(
    const unsigned short* __restrict__ Xc, const unsigned short* __restrict__ W1T,
    const unsigned short* __restrict__ W2T, const float* __restrict__ b1,
    const float* __restrict__ b2, unsigned short* __restrict__ Hbuf,
    const int* __restrict__ counts, const int* __restrict__ rowTok) {
    int u = xcd_swz(blockIdx.x, GRID1);
    int bx = u / (H_DIM / BN1);
    int by = u - bx * (H_DIM / BN1);
    int e, g0, vr;
    if (!tile_map(counts, bx, e, g0, vr)) return;
    int n0 = by * BN1;

    __shared__ __align__(16) unsigned short sA[BM * BK];
    __shared__ __align__(16) unsigned short sB1[BN1 * BK];
    __shared__ __align__(16) unsigned short sB2[BN1 * BK];

    int tid = threadIdx.x, lane = tid & 63, w = tid >> 6;
    int wm = w >> 2, wn = w & 3;
    int lr = lane & 15, lh = lane >> 4;

    // per-thread A-row token lookup (2 rows per thread)
    int tokA[2];
#pragma unroll
    for (int ra = 0; ra < 2; ra++) {
        int row = (ra * 8192 + tid * 16) >> 7;
        int gi = g0 + row; if (gi > NP - 1) gi = NP - 1;
        tokA[ra] = rowTok[gi];
    }

    f32x4 acc1[4][2], acc2[4][2];
#pragma unroll
    for (int a = 0; a < 4; a++)
#pragma unroll
        for (int b = 0; b < 2; b++) { acc1[a][b] = (f32x4)0.f; acc2[a][b] = (f32x4)0.f; }

    const unsigned short* W1e = W1T + (size_t)e * H_DIM * D_IN;
    const unsigned short* W2e = W2T + (size_t)e * H_DIM * D_IN;

    for (int kt = 0; kt < D_IN / BK; ++kt) {
        int kb = kt * BK;
#pragma unroll
        for (int ra = 0; ra < 2; ra++) {
            int o = ra * 8192 + tid * 16;
            int row = o >> 7;
            int c = ((o >> 4) & 7) ^ (row & 7);
            gload_lds16(Xc + (size_t)tokA[ra] * D_IN + kb + c * 8, (char*)sA + o);
        }
#pragma unroll
        for (int rb2 = 0; rb2 < 2; rb2++) {
            int o = rb2 * 8192 + tid * 16;
            int row = o >> 7;
            int c = ((o >> 4) & 7) ^ (row & 7);
            size_t src = (size_t)(n0 + row) * D_IN + kb + c * 8;
            gload_lds16(W1e + src, (char*)sB1 + o);
            gload_lds16(W2e + src, (char*)sB2 + o);
        }
        asm volatile("s_waitcnt vmcnt(0)" ::: "memory");
        __syncthreads();
#pragma unroll
        for (int ks = 0; ks < 2; ++ks) {
            int sb = ks * 4 + lh;
            s16x8 av[4];
#pragma unroll
            for (int mf = 0; mf < 4; ++mf) {
                int r = wm * 64 + mf * 16 + lr;
                av[mf] = *(const s16x8*)&sA[r * 64 + ((sb ^ (r & 7)) << 3)];
            }
#pragma unroll
            for (int nf = 0; nf < 2; ++nf) {
                int n = wn * 32 + nf * 16 + lr;
                int off = n * 64 + ((sb ^ (n & 7)) << 3);
                s16x8 bv1 = *(const s16x8*)&sB1[off];
                s16x8 bv2 = *(const s16x8*)&sB2[off];
#pragma unroll
                for (int mf = 0; mf < 4; ++mf) {
                    acc1[mf][nf] = __builtin_amdgcn_mfma_f32_16x16x32_bf16(av[mf], bv1, acc1[mf][nf], 0, 0, 0);
                    acc2[mf][nf] = __builtin_amdgcn_mfma_f32_16x16x32_bf16(av[mf], bv2, acc2[mf][nf], 0, 0, 0);
                }
            }
        }
        __syncthreads();
    }
#pragma unroll
    for (int mf = 0; mf < 4; ++mf) {
        int rbase = wm * 64 + mf * 16 + lh * 4;
#pragma unroll
        for (int nf = 0; nf < 2; ++nf) {
            int n = n0 + wn * 32 + nf * 16 + lr;
            float bb1 = b1[e * H_DIM + n], bb2 = b2[e * H_DIM + n];
#pragma unroll
            for (int j = 0; j < 4; ++j) {
                int r = rbase + j;
                if (r < vr) {
                    float x1 = acc1[mf][nf][j] + bb1;
                    float x2 = acc2[mf][nf][j] + bb2;
                    float h = x1 / (1.f + __expf(-x1)) * x2;
                    Hbuf[(size_t)(g0 + r) * H_DIM + n] = f2bf(h);
                }
            }
        }
    }
}

// ---- ffn2: Y = gate * (H@W3 + b3), f32 out (R8/R11 structure) ----
__global__ __launch_bounds__(256) void ffn2_kernel(
    const unsigned short* __restrict__ Hbuf, const unsigned short* __restrict__ W3T,
    const float* __restrict__ b3, const float* __restrict__ rowGate,
    float* __restrict__ Ybuf, const int* __restrict__ counts) {
    int u = xcd_swz(blockIdx.x, GRID2);
    int bx = u / (D_IN / BN2);
    int by = u - bx * (D_IN / BN2);
    int e, g0, vr;
    if (!tile_map(counts, bx, e, g0, vr)) return;
    int n0 = by * BN2;

    __shared__ __align__(16) unsigned short sA[2][BM * BK];
    __shared__ __align__(16) unsigned short sB[2][BN2 * BK];

    int tid = threadIdx.x, lane = tid & 63, w = tid >> 6;
    int wm = w >> 1, wn = w & 1;
    int lr = lane & 15, lh = lane >> 4;

    f32x4 acc[4][4];
#pragma unroll
    for (int a = 0; a < 4; a++)
#pragma unroll
        for (int b = 0; b < 4; b++) acc[a][b] = (f32x4)0.f;

    const unsigned short* W3e = W3T + (size_t)e * D_IN * H_DIM;

    auto stage = [&](int buf, int kt) {
        int kb = kt * BK;
#pragma unroll
        for (int ca = 0; ca < 4; ca++) {
            int o = ca * 4096 + tid * 16;
            int row = o >> 7;
            int c = ((o >> 4) & 7) ^ (row & 7);
            int gr = g0 + row; if (gr > NP - 1) gr = NP - 1;
            gload_lds16(Hbuf + (size_t)gr * H_DIM + kb + c * 8, (char*)&sA[buf][0] + o);
        }
#pragma unroll
        for (int cb = 0; cb < 4; cb++) {
            int o = cb * 4096 + tid * 16;
            int row = o >> 7;
            int c = ((o >> 4) & 7) ^ (row & 7);
            gload_lds16(W3e + (size_t)(n0 + row) * H_DIM + kb + c * 8, (char*)&sB[buf][0] + o);
        }
    };

    const int NKT = H_DIM / BK;
    stage(0, 0);
    stage(1, 1);
    __builtin_amdgcn_sched_barrier(0);
#pragma unroll 1
    for (int kt = 0; kt < NKT; ++kt) {
        if (kt < NKT - 1) { asm volatile("s_waitcnt vmcnt(8)" ::: "memory"); }
        else              { asm volatile("s_waitcnt vmcnt(0)" ::: "memory"); }
        __builtin_amdgcn_s_barrier();
        __builtin_amdgcn_sched_barrier(0);
        int cur = kt & 1;
#pragma unroll
        for (int ks = 0; ks < 2; ++ks) {
            int sb = ks * 4 + lh;
            s16x8 av[4], bv[4];
#pragma unroll
            for (int mf = 0; mf < 4; ++mf) {
                int r = wm * 64 + mf * 16 + lr;
                av[mf] = *(const s16x8*)&sA[cur][r * 64 + ((sb ^ (r & 7)) << 3)];
            }
#pragma unroll
            for (int nf = 0; nf < 4; ++nf) {
                int n = wn * 64 + nf * 16 + lr;
                bv[nf] = *(const s16x8*)&sB[cur][n * 64 + ((sb ^ (n & 7)) << 3)];
            }
#pragma unroll
            for (int nf = 0; nf < 4; ++nf)
#pragma unroll
                for (int mf = 0; mf < 4; ++mf)
                    acc[mf][nf] = __builtin_amdgcn_mfma_f32_16x16x32_bf16(av[mf], bv[nf], acc[mf][nf], 0, 0, 0);
        }
        __builtin_amdgcn_sched_barrier(0);
        __builtin_amdgcn_s_barrier();
        if (kt + 2 < NKT) { stage(cur, kt + 2); __builtin_amdgcn_sched_barrier(0); }
    }
#pragma unroll
    for (int mf = 0; mf < 4; ++mf) {
        int rbase = wm * 64 + mf * 16 + lh * 4;
#pragma unroll
        for (int nf = 0; nf < 4; ++nf) {
            int n = n0 + wn * 64 + nf * 16 + lr;
            float bb = b3[e * D_IN + n];
#pragma unroll
            for (int j = 0; j < 4; ++j) {
                int r = rbase + j;
                if (r < vr) {
                    float g = rowGate[g0 + r];
                    Ybuf[(size_t)(g0 + r) * D_IN + n] = g * (acc[mf][nf][j] + bb);
                }
            }
        }
    }
}

// ---- combine ----
__global__ __launch_bounds__(192) void combine_kernel(
    const float* __restrict__ Ybuf, const int* __restrict__ pairPos, float* __restrict__ out) {
    int t = blockIdx.x, i = threadIdx.x;
    int p0 = pairPos[t * 2], p1 = pairPos[t * 2 + 1];
    float4 a = ((const float4*)(Ybuf + (size_t)p0 * D_IN))[i];
    float4 b = ((const float4*)(Ybuf + (size_t)p1 * D_IN))[i];
    float4 r; r.x = a.x + b.x; r.y = a.y + b.y; r.z = a.z + b.z; r.w = a.w + b.w;
    ((float4*)(out + (size_t)t * D_IN))[i] = r;
}

extern "C" void kernel_launch(void* const* d_in, const int* in_sizes, int n_in,
                              void* d_out, int out_size, void* d_ws, size_t ws_size,
                              hipStream_t stream) {
    const float* x  = (const float*)d_in[0];
    const float* rw = (const float*)d_in[1];
    const float* rb = (const float*)d_in[2];
    const float* w1 = (const float*)d_in[3];
    const float* b1 = (const float*)d_in[4];
    const float* w2 = (const float*)d_in[5];
    const float* b2 = (const float*)d_in[6];
    const float* w3 = (const float*)d_in[7];
    const float* b3 = (const float*)d_in[8];
    float* out = (float*)d_out;

    char* ws = (char*)d_ws;
    const size_t sW = (size_t)N_EXP * H_DIM * D_IN * 2;
    unsigned short* W1T = (unsigned short*)(ws);
    unsigned short* W2T = (unsigned short*)(ws + sW);
    unsigned short* W3T = (unsigned short*)(ws + 2 * sW);
    unsigned short* Xc  = (unsigned short*)(ws + 3 * sW);                       // 6.3 MB (token order)
    unsigned short* Hb  = (unsigned short*)(ws + 3 * sW + (size_t)N_TOK * D_IN * 2);
    float* Yb = (float*)(ws + 3 * sW + (size_t)N_TOK * D_IN * 2 + (size_t)NP * H_DIM * 2);
    char* meta = (char*)(Yb + (size_t)NP * D_IN);
    int*   counts  = (int*)(meta + 0);
    int*   top1    = (int*)(meta + 32);
    float* psum    = (float*)(meta + 64);
    int*   cursors = (int*)(meta + 96);
    int*   tk_e    = (int*)(meta + 1024);
    float* tk_w    = (float*)(meta + 1024 + 32768);
    int*   rowTok  = (int*)(meta + 1024 + 65536);
    float* rowGate = (float*)(meta + 1024 + 98304);
    int*   pairPos = (int*)(meta + 1024 + 131072);
    size_t need = (size_t)(meta - ws) + 1024 + 163840;
    if (ws_size < need) return;

    hipMemsetAsync(meta, 0, 128, stream);
    xcvt_kernel<<<N_TOK, 192, 0, stream>>>(x, Xc);
    router_kernel<<<N_TOK / 16, 256, 0, stream>>>(x, rw, rb, counts, top1, psum, tk_e, tk_w);
    transpose_kernel<<<NT_BLKS, 256, 0, stream>>>(w1, w2, w3, W1T, W2T, W3T);
    scatter_kernel<<<N_TOK / 64, 64, 0, stream>>>(
        tk_e, tk_w, counts, cursors, rowTok, rowGate, pairPos,
        top1, psum, out + (size_t)N_TOK * D_IN);
    ffn1_kernel<<<GRID1, 512, 0, stream>>>(Xc, W1T, W2T, b1, b2, Hb, counts, rowTok);
    ffn2_kernel<<<GRID2, 256, 0, stream>>>(Hb, W3T, b3, rowGate, Yb, counts);
    combine_kernel<<<N_TOK, 192, 0, stream>>>(Yb, pairPos, out);
}

// Round 14
// 292.029 us; speedup vs baseline: 1.0639x; 1.0110x over previous
//
#include <hip/hip_runtime.h>
#include <hip/hip_bf16.h>
#include <math.h>

#define N_TOK 4096
#define D_IN  768
#define N_EXP 8
#define NP    8192      // N_TOK * TOPK
#define H_DIM 3072
#define BM    128
#define BK    64
#define BN1   128
#define BN2   128
#define MAXT  72
#define GRID1 (MAXT * (H_DIM / BN1))   // 1728, div by 8
#define GRID2 (MAXT * (D_IN / BN2))    // 432, div by 8
#define NT_BLKS 3456                   // 24 mats * 144 tiles (64 rows x 256 cols)
#define TPE   144
#define PREP_R (NT_BLKS + 256)         // router block range end
#define PREP_ALL (PREP_R + 1024)       // + xcvt blocks (4 tokens each)

typedef float f32x4 __attribute__((ext_vector_type(4)));
typedef short s16x8 __attribute__((ext_vector_type(8)));

__device__ __forceinline__ unsigned short f2bf(float f) {
    unsigned int u = __builtin_bit_cast(unsigned int, f);
    u += 0x7fffu + ((u >> 16) & 1u);
    return (unsigned short)(u >> 16);
}

__device__ __forceinline__ void gload_lds16(const void* g, void* l) {
    __builtin_amdgcn_global_load_lds(
        (const __attribute__((address_space(1))) unsigned int*)g,
        (__attribute__((address_space(3))) unsigned int*)l, 16, 0, 0);
}

__device__ __forceinline__ int xcd_swz(int bid, int nblk) {
    int chunk = nblk >> 3;
    return (bid & 7) * chunk + (bid >> 3);
}

__device__ __forceinline__ bool tile_map(const int* counts, int bx, int& e, int& g0, int& vr) {
    int off = 0, nt = 0;
    e = -1;
    int lb = 0, cnt = 0;
#pragma unroll
    for (int ee = 0; ee < N_EXP; ee++) {
        int c = counts[ee];
        int t = (c + BM - 1) >> 7;
        if (bx >= nt && bx < nt + t) { e = ee; lb = (bx - nt) * BM; g0 = off + lb; cnt = c; }
        nt += t; off += c;
    }
    if (e < 0) return false;
    vr = cnt - lb; if (vr > BM) vr = BM;
    return true;
}

// ---- prep2: transpose (3456) + router (256) + xcvt (1024) in ONE launch ----
// All independent; router LDS is only 96 B so no occupancy tax (R9 lesson).
__global__ __launch_bounds__(256) void prep2_kernel(
    const float* __restrict__ w1, const float* __restrict__ w2, const float* __restrict__ w3,
    unsigned short* __restrict__ W1T, unsigned short* __restrict__ W2T,
    unsigned short* __restrict__ W3T,
    const float* __restrict__ x, const float* __restrict__ rw, const float* __restrict__ rb,
    int* counts, int* top1cnt, float* probs_sum, int* tk_e, float* tk_w,
    unsigned short* __restrict__ Xc) {
    int bid = blockIdx.x, tid = threadIdx.x;

    if (bid < NT_BLKS) {
        // ---- weight transpose: register-only, 64x256 src tile, 2 chains/thread ----
        int z = bid / TPE;
        int tt = bid - z * TPE;
        const float* s;
        unsigned short* d;
        int R, C, tc;
        if (z < 8)       { s = w1 + (size_t)z * D_IN * H_DIM;        d = W1T + (size_t)z * H_DIM * D_IN;        R = D_IN;  C = H_DIM; tc = 12; }
        else if (z < 16) { s = w2 + (size_t)(z - 8) * D_IN * H_DIM;  d = W2T + (size_t)(z - 8) * H_DIM * D_IN;  R = D_IN;  C = H_DIM; tc = 12; }
        else             { s = w3 + (size_t)(z - 16) * H_DIM * D_IN; d = W3T + (size_t)(z - 16) * D_IN * H_DIM; R = H_DIM; C = D_IN;  tc = 3;  }
        int r0 = (tt / tc) * 64, c0 = (tt % tc) * 256;
        int lane = tid & 63, w = tid >> 6;
        int tx = lane & 7, ty = lane >> 3;
        int cb = c0 + 32 * w + 4 * tx;
        int rb2 = r0 + 8 * ty;
        const float* sp  = s + (size_t)rb2 * C + cb;
        const float* sp2 = sp + 128;
        f32x4 L[8], M[8];
#pragma unroll
        for (int i = 0; i < 8; i++)
            L[i] = __builtin_nontemporal_load((const f32x4*)(sp + (size_t)i * C));
#pragma unroll
        for (int i = 0; i < 8; i++)
            M[i] = __builtin_nontemporal_load((const f32x4*)(sp2 + (size_t)i * C));
#pragma unroll
        for (int j = 0; j < 4; j++) {
            s16x8 o;
#pragma unroll
            for (int k = 0; k < 8; k++) o[k] = (short)f2bf(L[k][j]);
            *(s16x8*)&d[(size_t)(cb + j) * R + rb2] = o;
        }
#pragma unroll
        for (int j = 0; j < 4; j++) {
            s16x8 o;
#pragma unroll
            for (int k = 0; k < 8; k++) o[k] = (short)f2bf(M[k][j]);
            *(s16x8*)&d[(size_t)(cb + 128 + j) * R + rb2] = o;
        }
    } else if (bid < PREP_R) {
        // ---- router: 16 lanes per token (48 dims each), shfl reduce ----
        __shared__ float s_ps[N_EXP];
        __shared__ int s_cnt[N_EXP], s_t1[N_EXP];
        int rbid = bid - NT_BLKS;
        if (tid < N_EXP) { s_ps[tid] = 0.f; s_cnt[tid] = 0; s_t1[tid] = 0; }
        __syncthreads();
        int tok = rbid * 16 + (tid >> 4);
        int part = tid & 15;
        float acc[N_EXP];
#pragma unroll
        for (int e = 0; e < N_EXP; e++) acc[e] = 0.f;
        const float* xr = x + (size_t)tok * D_IN + part * 48;
        const float* rwr = rw + (size_t)part * 48 * N_EXP;
        for (int dd = 0; dd < 48; dd++) {
            float xv = xr[dd];
            f32x4 ra = *(const f32x4*)(rwr + dd * N_EXP);
            f32x4 rbv = *(const f32x4*)(rwr + dd * N_EXP + 4);
            acc[0] += xv * ra[0]; acc[1] += xv * ra[1]; acc[2] += xv * ra[2]; acc[3] += xv * ra[3];
            acc[4] += xv * rbv[0]; acc[5] += xv * rbv[1]; acc[6] += xv * rbv[2]; acc[7] += xv * rbv[3];
        }
#pragma unroll
        for (int s = 1; s < 16; s <<= 1)
#pragma unroll
            for (int e = 0; e < N_EXP; e++) acc[e] += __shfl_xor(acc[e], s, 64);
        if (part == 0) {
            float p[N_EXP], m, ssum = 0.f;
#pragma unroll
            for (int e = 0; e < N_EXP; e++) acc[e] += rb[e];
            m = acc[0];
#pragma unroll
            for (int e = 1; e < N_EXP; e++) m = fmaxf(m, acc[e]);
#pragma unroll
            for (int e = 0; e < N_EXP; e++) { p[e] = __expf(acc[e] - m); ssum += p[e]; }
            float inv = 1.f / ssum;
#pragma unroll
            for (int e = 0; e < N_EXP; e++) p[e] *= inv;
            int e0 = 0;
#pragma unroll
            for (int e = 1; e < N_EXP; e++) if (p[e] > p[e0]) e0 = e;
            int e1 = (e0 == 0) ? 1 : 0;
#pragma unroll
            for (int e = 0; e < N_EXP; e++) if (e != e0 && p[e] > p[e1]) e1 = e;
            float denom = 1.f / (p[e0] + p[e1]);
            tk_e[tok * 2] = e0; tk_e[tok * 2 + 1] = e1;
            tk_w[tok * 2] = p[e0] * denom; tk_w[tok * 2 + 1] = p[e1] * denom;
            atomicAdd(&s_cnt[e0], 1); atomicAdd(&s_cnt[e1], 1); atomicAdd(&s_t1[e0], 1);
#pragma unroll
            for (int e = 0; e < N_EXP; e++) atomicAdd(&s_ps[e], p[e]);
        }
        __syncthreads();
        if (tid < N_EXP) {
            atomicAdd(&counts[tid], s_cnt[tid]);
            atomicAdd(&top1cnt[tid], s_t1[tid]);
            atomicAdd(&probs_sum[tid], s_ps[tid]);
        }
    } else {
        // ---- xcvt: 4 tokens per block, 3 float4 per thread ----
        int cb = bid - PREP_R;
        size_t base = (size_t)cb * 768;   // in float4 units
#pragma unroll
        for (int it = 0; it < 3; it++) {
            size_t idx = base + tid + it * 256;
            float4 v = ((const float4*)x)[idx];
            unsigned long long pk = (unsigned long long)f2bf(v.x)
                                  | ((unsigned long long)f2bf(v.y) << 16)
                                  | ((unsigned long long)f2bf(v.z) << 32)
                                  | ((unsigned long long)f2bf(v.w) << 48);
            ((unsigned long long*)Xc)[idx] = pk;
        }
    }
}

// ---- scatter: permutation via inline prefix of counts; block0 computes aux ----
__global__ __launch_bounds__(64) void scatter_kernel(
    const int* __restrict__ tk_e, const float* __restrict__ tk_w,
    const int* __restrict__ counts, int* cursors,
    int* rowTok, float* rowGate, int* pairPos,
    const int* __restrict__ top1cnt, const float* __restrict__ probs_sum, float* aux_out) {
    int tid = threadIdx.x;
    int tok = blockIdx.x * 64 + tid;
    int segOff[N_EXP];
    int off = 0;
#pragma unroll
    for (int e = 0; e < N_EXP; e++) { segOff[e] = off; off += counts[e]; }
#pragma unroll
    for (int k = 0; k < 2; k++) {
        int e = tk_e[tok * 2 + k];
        int pos = segOff[e] + atomicAdd(&cursors[e], 1);
        rowTok[pos] = tok;
        rowGate[pos] = tk_w[tok * 2 + k];
        pairPos[tok * 2 + k] = pos;
    }
    if (blockIdx.x == 0 && tid == 0) {
        float aux = 0.f;
#pragma unroll
        for (int e = 0; e < N_EXP; e++) aux += (float)top1cnt[e] * probs_sum[e];
        aux_out[0] = (float)N_EXP * aux / ((float)N_TOK * (float)N_TOK);
    }
}

// ---- ffn1: H = silu(X@W1+b1) * (X@W2+b2), bf16 out (R11/R13 structure) ----
__global__ __launch_bounds__(512) void ffn1_kernel(
    const unsigned short* __restrict__ Xc, const unsigned short* __restrict__ W1T,
    const unsigned short* __restrict__ W2T, const float* __restrict__ b1,
    const float* __restrict__ b2, unsigned short* __restrict__ Hbuf,
    const int* __restrict__ counts, const int* __restrict__ rowTok) {
    int u = xcd_swz(blockIdx.x, GRID1);
    int bx = u / (H_DIM / BN1);
    int by = u - bx * (H_DIM / BN1);
    int e, g0, vr;
    if (!tile_map(counts, bx, e, g0, vr)) return;
    int n0 = by * BN1;

    __shared__ __align__(16) unsigned short sA[BM * BK];
    __shared__ __align__(16) unsigned short sB1[BN1 * BK];
    __shared__ __align__(16) unsigned short sB2[BN1 * BK];

    int tid = threadIdx.x, lane = tid & 63, w = tid >> 6;
    int wm = w >> 2, wn = w & 3;
    int lr = lane & 15, lh = lane >> 4;

    int tokA[2];
#pragma unroll
    for (int ra = 0; ra < 2; ra++) {
        int row = (ra * 8192 + tid * 16) >> 7;
        int gi = g0 + row; if (gi > NP - 1) gi = NP - 1;
        tokA[ra] = rowTok[gi];
    }

    f32x4 acc1[4][2], acc2[4][2];
#pragma unroll
    for (int a = 0; a < 4; a++)
#pragma unroll
        for (int b = 0; b < 2; b++) { acc1[a][b] = (f32x4)0.f; acc2[a][b] = (f32x4)0.f; }

    const unsigned short* W1e = W1T + (size_t)e * H_DIM * D_IN;
    const unsigned short* W2e = W2T + (size_t)e * H_DIM * D_IN;

    for (int kt = 0; kt < D_IN / BK; ++kt) {
        int kb = kt * BK;
#pragma unroll
        for (int ra = 0; ra < 2; ra++) {
            int o = ra * 8192 + tid * 16;
            int row = o >> 7;
            int c = ((o >> 4) & 7) ^ (row & 7);
            gload_lds16(Xc + (size_t)tokA[ra] * D_IN + kb + c * 8, (char*)sA + o);
        }
#pragma unroll
        for (int rb2 = 0; rb2 < 2; rb2++) {
            int o = rb2 * 8192 + tid * 16;
            int row = o >> 7;
            int c = ((o >> 4) & 7) ^ (row & 7);
            size_t src = (size_t)(n0 + row) * D_IN + kb + c * 8;
            gload_lds16(W1e + src, (char*)sB1 + o);
            gload_lds16(W2e + src, (char*)sB2 + o);
        }
        asm volatile("s_waitcnt vmcnt(0)" ::: "memory");
        __syncthreads();
#pragma unroll
        for (int ks = 0; ks < 2; ++ks) {
            int sb = ks * 4 + lh;
            s16x8 av[4];
#pragma unroll
            for (int mf = 0; mf < 4; ++mf) {
                int r = wm * 64 + mf * 16 + lr;
                av[mf] = *(const s16x8*)&sA[r * 64 + ((sb ^ (r & 7)) << 3)];
            }
#pragma unroll
            for (int nf = 0; nf < 2; ++nf) {
                int n = wn * 32 + nf * 16 + lr;
                int off = n * 64 + ((sb ^ (n & 7)) << 3);
                s16x8 bv1 = *(const s16x8*)&sB1[off];
                s16x8 bv2 = *(const s16x8*)&sB2[off];
#pragma unroll
                for (int mf = 0; mf < 4; ++mf) {
                    acc1[mf][nf] = __builtin_amdgcn_mfma_f32_16x16x32_bf16(av[mf], bv1, acc1[mf][nf], 0, 0, 0);
                    acc2[mf][nf] = __builtin_amdgcn_mfma_f32_16x16x32_bf16(av[mf], bv2, acc2[mf][nf], 0, 0, 0);
                }
            }
        }
        __syncthreads();
    }
#pragma unroll
    for (int mf = 0; mf < 4; ++mf) {
        int rbase = wm * 64 + mf * 16 + lh * 4;
#pragma unroll
        for (int nf = 0; nf < 2; ++nf) {
            int n = n0 + wn * 32 + nf * 16 + lr;
            float bb1 = b1[e * H_DIM + n], bb2 = b2[e * H_DIM + n];
#pragma unroll
            for (int j = 0; j < 4; ++j) {
                int r = rbase + j;
                if (r < vr) {
                    float x1 = acc1[mf][nf][j] + bb1;
                    float x2 = acc2[mf][nf][j] + bb2;
                    float h = x1 / (1.f + __expf(-x1)) * x2;
                    Hbuf[(size_t)(g0 + r) * H_DIM + n] = f2bf(h);
                }
            }
        }
    }
}

// ---- ffn2: Y = gate * (H@W3 + b3), f32 out (R8/R11 structure) ----
__global__ __launch_bounds__(256) void ffn2_kernel(
    const unsigned short* __restrict__ Hbuf, const unsigned short* __restrict__ W3T,
    const float* __restrict__ b3, const float* __restrict__ rowGate,
    float* __restrict__ Ybuf, const int* __restrict__ counts) {
    int u = xcd_swz(blockIdx.x, GRID2);
    int bx = u / (D_IN / BN2);
    int by = u - bx * (D_IN / BN2);
    int e, g0, vr;
    if (!tile_map(counts, bx, e, g0, vr)) return;
    int n0 = by * BN2;

    __shared__ __align__(16) unsigned short sA[2][BM * BK];
    __shared__ __align__(16) unsigned short sB[2][BN2 * BK];

    int tid = threadIdx.x, lane = tid & 63, w = tid >> 6;
    int wm = w >> 1, wn = w & 1;
    int lr = lane & 15, lh = lane >> 4;

    f32x4 acc[4][4];
#pragma unroll
    for (int a = 0; a < 4; a++)
#pragma unroll
        for (int b = 0; b < 4; b++) acc[a][b] = (f32x4)0.f;

    const unsigned short* W3e = W3T + (size_t)e * D_IN * H_DIM;

    auto stage = [&](int buf, int kt) {
        int kb = kt * BK;
#pragma unroll
        for (int ca = 0; ca < 4; ca++) {
            int o = ca * 4096 + tid * 16;
            int row = o >> 7;
            int c = ((o >> 4) & 7) ^ (row & 7);
            int gr = g0 + row; if (gr > NP - 1) gr = NP - 1;
            gload_lds16(Hbuf + (size_t)gr * H_DIM + kb + c * 8, (char*)&sA[buf][0] + o);
        }
#pragma unroll
        for (int cb = 0; cb < 4; cb++) {
            int o = cb * 4096 + tid * 16;
            int row = o >> 7;
            int c = ((o >> 4) & 7) ^ (row & 7);
            gload_lds16(W3e + (size_t)(n0 + row) * H_DIM + kb + c * 8, (char*)&sB[buf][0] + o);
        }
    };

    const int NKT = H_DIM / BK;
    stage(0, 0);
    stage(1, 1);
    __builtin_amdgcn_sched_barrier(0);
#pragma unroll 1
    for (int kt = 0; kt < NKT; ++kt) {
        if (kt < NKT - 1) { asm volatile("s_waitcnt vmcnt(8)" ::: "memory"); }
        else              { asm volatile("s_waitcnt vmcnt(0)" ::: "memory"); }
        __builtin_amdgcn_s_barrier();
        __builtin_amdgcn_sched_barrier(0);
        int cur = kt & 1;
#pragma unroll
        for (int ks = 0; ks < 2; ++ks) {
            int sb = ks * 4 + lh;
            s16x8 av[4], bv[4];
#pragma unroll
            for (int mf = 0; mf < 4; ++mf) {
                int r = wm * 64 + mf * 16 + lr;
                av[mf] = *(const s16x8*)&sA[cur][r * 64 + ((sb ^ (r & 7)) << 3)];
            }
#pragma unroll
            for (int nf = 0; nf < 4; ++nf) {
                int n = wn * 64 + nf * 16 + lr;
                bv[nf] = *(const s16x8*)&sB[cur][n * 64 + ((sb ^ (n & 7)) << 3)];
            }
#pragma unroll
            for (int nf = 0; nf < 4; ++nf)
#pragma unroll
                for (int mf = 0; mf < 4; ++mf)
                    acc[mf][nf] = __builtin_amdgcn_mfma_f32_16x16x32_bf16(av[mf], bv[nf], acc[mf][nf], 0, 0, 0);
        }
        __builtin_amdgcn_sched_barrier(0);
        __builtin_amdgcn_s_barrier();
        if (kt + 2 < NKT) { stage(cur, kt + 2); __builtin_amdgcn_sched_barrier(0); }
    }
#pragma unroll
    for (int mf = 0; mf < 4; ++mf) {
        int rbase = wm * 64 + mf * 16 + lh * 4;
#pragma unroll
        for (int nf = 0; nf < 4; ++nf) {
            int n = n0 + wn * 64 + nf * 16 + lr;
            float bb = b3[e * D_IN + n];
#pragma unroll
            for (int j = 0; j < 4; ++j) {
                int r = rbase + j;
                if (r < vr) {
                    float g = rowGate[g0 + r];
                    Ybuf[(size_t)(g0 + r) * D_IN + n] = g * (acc[mf][nf][j] + bb);
                }
            }
        }
    }
}

// ---- combine ----
__global__ __launch_bounds__(192) void combine_kernel(
    const float* __restrict__ Ybuf, const int* __restrict__ pairPos, float* __restrict__ out) {
    int t = blockIdx.x, i = threadIdx.x;
    int p0 = pairPos[t * 2], p1 = pairPos[t * 2 + 1];
    float4 a = ((const float4*)(Ybuf + (size_t)p0 * D_IN))[i];
    float4 b = ((const float4*)(Ybuf + (size_t)p1 * D_IN))[i];
    float4 r; r.x = a.x + b.x; r.y = a.y + b.y; r.z = a.z + b.z; r.w = a.w + b.w;
    ((float4*)(out + (size_t)t * D_IN))[i] = r;
}

extern "C" void kernel_launch(void* const* d_in, const int* in_sizes, int n_in,
                              void* d_out, int out_size, void* d_ws, size_t ws_size,
                              hipStream_t stream) {
    const float* x  = (const float*)d_in[0];
    const float* rw = (const float*)d_in[1];
    const float* rb = (const float*)d_in[2];
    const float* w1 = (const float*)d_in[3];
    const float* b1 = (const float*)d_in[4];
    const float* w2 = (const float*)d_in[5];
    const float* b2 = (const float*)d_in[6];
    const float* w3 = (const float*)d_in[7];
    const float* b3 = (const float*)d_in[8];
    float* out = (float*)d_out;

    char* ws = (char*)d_ws;
    const size_t sW = (size_t)N_EXP * H_DIM * D_IN * 2;
    unsigned short* W1T = (unsigned short*)(ws);
    unsigned short* W2T = (unsigned short*)(ws + sW);
    unsigned short* W3T = (unsigned short*)(ws + 2 * sW);
    unsigned short* Xc  = (unsigned short*)(ws + 3 * sW);                       // 6.3 MB (token order)
    unsigned short* Hb  = (unsigned short*)(ws + 3 * sW + (size_t)N_TOK * D_IN * 2);
    float* Yb = (float*)(ws + 3 * sW + (size_t)N_TOK * D_IN * 2 + (size_t)NP * H_DIM * 2);
    char* meta = (char*)(Yb + (size_t)NP * D_IN);
    int*   counts  = (int*)(meta + 0);
    int*   top1    = (int*)(meta + 32);
    float* psum    = (float*)(meta + 64);
    int*   cursors = (int*)(meta + 96);
    int*   tk_e    = (int*)(meta + 1024);
    float* tk_w    = (float*)(meta + 1024 + 32768);
    int*   rowTok  = (int*)(meta + 1024 + 65536);
    float* rowGate = (float*)(meta + 1024 + 98304);
    int*   pairPos = (int*)(meta + 1024 + 131072);
    size_t need = (size_t)(meta - ws) + 1024 + 163840;
    if (ws_size < need) return;

    hipMemsetAsync(meta, 0, 128, stream);
    prep2_kernel<<<PREP_ALL, 256, 0, stream>>>(
        w1, w2, w3, W1T, W2T, W3T, x, rw, rb, counts, top1, psum, tk_e, tk_w, Xc);
    scatter_kernel<<<N_TOK / 64, 64, 0, stream>>>(
        tk_e, tk_w, counts, cursors, rowTok, rowGate, pairPos,
        top1, psum, out + (size_t)N_TOK * D_IN);
    ffn1_kernel<<<GRID1, 512, 0, stream>>>(Xc, W1T, W2T, b1, b2, Hb, counts, rowTok);
    ffn2_kernel<<<GRID2, 256, 0, stream>>>(Hb, W3T, b3, rowGate, Yb, counts);
    combine_kernel<<<N_TOK, 192, 0, stream>>>(Yb, pairPos, out);
}

// Round 15
// 286.363 us; speedup vs baseline: 1.0849x; 1.0198x over previous
//
#include <hip/hip_runtime.h>
#include <hip/hip_bf16.h>
#include <math.h>

#define N_TOK 4096
#define D_IN  768
#define N_EXP 8
#define NP    8192      // N_TOK * TOPK
#define H_DIM 3072
#define BM    128
#define BK    64
#define BN1   128
#define BN2   128
#define MAXT  72
#define GRID1 (MAXT * (H_DIM / BN1))   // 1728, div by 8
#define GRID2 (MAXT * (D_IN / BN2))    // 432, div by 8
#define NT_BLKS 3456                   // 24 mats * 144 tiles (64 rows x 256 cols)
#define TPE   144
#define PREP_R (NT_BLKS + 256)         // router block range end
#define PREP_ALL (PREP_R + 1024)       // + xcvt blocks (4 tokens each)

typedef float f32x4 __attribute__((ext_vector_type(4)));
typedef short s16x8 __attribute__((ext_vector_type(8)));

__device__ __forceinline__ unsigned short f2bf(float f) {
    unsigned int u = __builtin_bit_cast(unsigned int, f);
    u += 0x7fffu + ((u >> 16) & 1u);
    return (unsigned short)(u >> 16);
}

__device__ __forceinline__ void gload_lds16(const void* g, void* l) {
    __builtin_amdgcn_global_load_lds(
        (const __attribute__((address_space(1))) unsigned int*)g,
        (__attribute__((address_space(3))) unsigned int*)l, 16, 0, 0);
}

__device__ __forceinline__ int xcd_swz(int bid, int nblk) {
    int chunk = nblk >> 3;
    return (bid & 7) * chunk + (bid >> 3);
}

__device__ __forceinline__ bool tile_map(const int* counts, int bx, int& e, int& g0, int& vr) {
    int off = 0, nt = 0;
    e = -1;
    int lb = 0, cnt = 0;
#pragma unroll
    for (int ee = 0; ee < N_EXP; ee++) {
        int c = counts[ee];
        int t = (c + BM - 1) >> 7;
        if (bx >= nt && bx < nt + t) { e = ee; lb = (bx - nt) * BM; g0 = off + lb; cnt = c; }
        nt += t; off += c;
    }
    if (e < 0) return false;
    vr = cnt - lb; if (vr > BM) vr = BM;
    return true;
}

// ---- prep2: transpose (3456) + router (256) + xcvt (1024) in ONE launch ----
__global__ __launch_bounds__(256) void prep2_kernel(
    const float* __restrict__ w1, const float* __restrict__ w2, const float* __restrict__ w3,
    unsigned short* __restrict__ W1T, unsigned short* __restrict__ W2T,
    unsigned short* __restrict__ W3T,
    const float* __restrict__ x, const float* __restrict__ rw, const float* __restrict__ rb,
    int* counts, int* top1cnt, float* probs_sum, int* tk_e, float* tk_w,
    unsigned short* __restrict__ Xc) {
    int bid = blockIdx.x, tid = threadIdx.x;

    if (bid < NT_BLKS) {
        int z = bid / TPE;
        int tt = bid - z * TPE;
        const float* s;
        unsigned short* d;
        int R, C, tc;
        if (z < 8)       { s = w1 + (size_t)z * D_IN * H_DIM;        d = W1T + (size_t)z * H_DIM * D_IN;        R = D_IN;  C = H_DIM; tc = 12; }
        else if (z < 16) { s = w2 + (size_t)(z - 8) * D_IN * H_DIM;  d = W2T + (size_t)(z - 8) * H_DIM * D_IN;  R = D_IN;  C = H_DIM; tc = 12; }
        else             { s = w3 + (size_t)(z - 16) * H_DIM * D_IN; d = W3T + (size_t)(z - 16) * D_IN * H_DIM; R = H_DIM; C = D_IN;  tc = 3;  }
        int r0 = (tt / tc) * 64, c0 = (tt % tc) * 256;
        int lane = tid & 63, w = tid >> 6;
        int tx = lane & 7, ty = lane >> 3;
        int cb = c0 + 32 * w + 4 * tx;
        int rb2 = r0 + 8 * ty;
        const float* sp  = s + (size_t)rb2 * C + cb;
        const float* sp2 = sp + 128;
        f32x4 L[8], M[8];
#pragma unroll
        for (int i = 0; i < 8; i++)
            L[i] = __builtin_nontemporal_load((const f32x4*)(sp + (size_t)i * C));
#pragma unroll
        for (int i = 0; i < 8; i++)
            M[i] = __builtin_nontemporal_load((const f32x4*)(sp2 + (size_t)i * C));
#pragma unroll
        for (int j = 0; j < 4; j++) {
            s16x8 o;
#pragma unroll
            for (int k = 0; k < 8; k++) o[k] = (short)f2bf(L[k][j]);
            *(s16x8*)&d[(size_t)(cb + j) * R + rb2] = o;
        }
#pragma unroll
        for (int j = 0; j < 4; j++) {
            s16x8 o;
#pragma unroll
            for (int k = 0; k < 8; k++) o[k] = (short)f2bf(M[k][j]);
            *(s16x8*)&d[(size_t)(cb + 128 + j) * R + rb2] = o;
        }
    } else if (bid < PREP_R) {
        __shared__ float s_ps[N_EXP];
        __shared__ int s_cnt[N_EXP], s_t1[N_EXP];
        int rbid = bid - NT_BLKS;
        if (tid < N_EXP) { s_ps[tid] = 0.f; s_cnt[tid] = 0; s_t1[tid] = 0; }
        __syncthreads();
        int tok = rbid * 16 + (tid >> 4);
        int part = tid & 15;
        float acc[N_EXP];
#pragma unroll
        for (int e = 0; e < N_EXP; e++) acc[e] = 0.f;
        const float* xr = x + (size_t)tok * D_IN + part * 48;
        const float* rwr = rw + (size_t)part * 48 * N_EXP;
        for (int dd = 0; dd < 48; dd++) {
            float xv = xr[dd];
            f32x4 ra = *(const f32x4*)(rwr + dd * N_EXP);
            f32x4 rbv = *(const f32x4*)(rwr + dd * N_EXP + 4);
            acc[0] += xv * ra[0]; acc[1] += xv * ra[1]; acc[2] += xv * ra[2]; acc[3] += xv * ra[3];
            acc[4] += xv * rbv[0]; acc[5] += xv * rbv[1]; acc[6] += xv * rbv[2]; acc[7] += xv * rbv[3];
        }
#pragma unroll
        for (int s = 1; s < 16; s <<= 1)
#pragma unroll
            for (int e = 0; e < N_EXP; e++) acc[e] += __shfl_xor(acc[e], s, 64);
        if (part == 0) {
            float p[N_EXP], m, ssum = 0.f;
#pragma unroll
            for (int e = 0; e < N_EXP; e++) acc[e] += rb[e];
            m = acc[0];
#pragma unroll
            for (int e = 1; e < N_EXP; e++) m = fmaxf(m, acc[e]);
#pragma unroll
            for (int e = 0; e < N_EXP; e++) { p[e] = __expf(acc[e] - m); ssum += p[e]; }
            float inv = 1.f / ssum;
#pragma unroll
            for (int e = 0; e < N_EXP; e++) p[e] *= inv;
            int e0 = 0;
#pragma unroll
            for (int e = 1; e < N_EXP; e++) if (p[e] > p[e0]) e0 = e;
            int e1 = (e0 == 0) ? 1 : 0;
#pragma unroll
            for (int e = 0; e < N_EXP; e++) if (e != e0 && p[e] > p[e1]) e1 = e;
            float denom = 1.f / (p[e0] + p[e1]);
            tk_e[tok * 2] = e0; tk_e[tok * 2 + 1] = e1;
            tk_w[tok * 2] = p[e0] * denom; tk_w[tok * 2 + 1] = p[e1] * denom;
            atomicAdd(&s_cnt[e0], 1); atomicAdd(&s_cnt[e1], 1); atomicAdd(&s_t1[e0], 1);
#pragma unroll
            for (int e = 0; e < N_EXP; e++) atomicAdd(&s_ps[e], p[e]);
        }
        __syncthreads();
        if (tid < N_EXP) {
            atomicAdd(&counts[tid], s_cnt[tid]);
            atomicAdd(&top1cnt[tid], s_t1[tid]);
            atomicAdd(&probs_sum[tid], s_ps[tid]);
        }
    } else {
        int cb = bid - PREP_R;
        size_t base = (size_t)cb * 768;   // in float4 units
#pragma unroll
        for (int it = 0; it < 3; it++) {
            size_t idx = base + tid + it * 256;
            float4 v = ((const float4*)x)[idx];
            unsigned long long pk = (unsigned long long)f2bf(v.x)
                                  | ((unsigned long long)f2bf(v.y) << 16)
                                  | ((unsigned long long)f2bf(v.z) << 32)
                                  | ((unsigned long long)f2bf(v.w) << 48);
            ((unsigned long long*)Xc)[idx] = pk;
        }
    }
}

// ---- scatter ----
__global__ __launch_bounds__(64) void scatter_kernel(
    const int* __restrict__ tk_e, const float* __restrict__ tk_w,
    const int* __restrict__ counts, int* cursors,
    int* rowTok, float* rowGate, int* pairPos,
    const int* __restrict__ top1cnt, const float* __restrict__ probs_sum, float* aux_out) {
    int tid = threadIdx.x;
    int tok = blockIdx.x * 64 + tid;
    int segOff[N_EXP];
    int off = 0;
#pragma unroll
    for (int e = 0; e < N_EXP; e++) { segOff[e] = off; off += counts[e]; }
#pragma unroll
    for (int k = 0; k < 2; k++) {
        int e = tk_e[tok * 2 + k];
        int pos = segOff[e] + atomicAdd(&cursors[e], 1);
        rowTok[pos] = tok;
        rowGate[pos] = tk_w[tok * 2 + k];
        pairPos[tok * 2 + k] = pos;
    }
    if (blockIdx.x == 0 && tid == 0) {
        float aux = 0.f;
#pragma unroll
        for (int e = 0; e < N_EXP; e++) aux += (float)top1cnt[e] * probs_sum[e];
        aux_out[0] = (float)N_EXP * aux / ((float)N_TOK * (float)N_TOK);
    }
}

// ---- ffn1: H = silu(X@W1+b1) * (X@W2+b2), bf16 out (R13 structure) ----
// by-major XCD decode: 72 consecutive co-XCD blocks share one W-panel (L2 reuse).
__global__ __launch_bounds__(512) void ffn1_kernel(
    const unsigned short* __restrict__ Xc, const unsigned short* __restrict__ W1T,
    const unsigned short* __restrict__ W2T, const float* __restrict__ b1,
    const float* __restrict__ b2, unsigned short* __restrict__ Hbuf,
    const int* __restrict__ counts, const int* __restrict__ rowTok) {
    int u = xcd_swz(blockIdx.x, GRID1);
    int by = u / MAXT;          // W-panel index (24), slow within XCD chunk
    int bx = u - by * MAXT;     // M-tile index (72), fast
    int e, g0, vr;
    if (!tile_map(counts, bx, e, g0, vr)) return;
    int n0 = by * BN1;

    __shared__ __align__(16) unsigned short sA[BM * BK];
    __shared__ __align__(16) unsigned short sB1[BN1 * BK];
    __shared__ __align__(16) unsigned short sB2[BN1 * BK];

    int tid = threadIdx.x, lane = tid & 63, w = tid >> 6;
    int wm = w >> 2, wn = w & 3;
    int lr = lane & 15, lh = lane >> 4;

    int tokA[2];
#pragma unroll
    for (int ra = 0; ra < 2; ra++) {
        int row = (ra * 8192 + tid * 16) >> 7;
        int gi = g0 + row; if (gi > NP - 1) gi = NP - 1;
        tokA[ra] = rowTok[gi];
    }

    f32x4 acc1[4][2], acc2[4][2];
#pragma unroll
    for (int a = 0; a < 4; a++)
#pragma unroll
        for (int b = 0; b < 2; b++) { acc1[a][b] = (f32x4)0.f; acc2[a][b] = (f32x4)0.f; }

    const unsigned short* W1e = W1T + (size_t)e * H_DIM * D_IN;
    const unsigned short* W2e = W2T + (size_t)e * H_DIM * D_IN;

    for (int kt = 0; kt < D_IN / BK; ++kt) {
        int kb = kt * BK;
#pragma unroll
        for (int ra = 0; ra < 2; ra++) {
            int o = ra * 8192 + tid * 16;
            int row = o >> 7;
            int c = ((o >> 4) & 7) ^ (row & 7);
            gload_lds16(Xc + (size_t)tokA[ra] * D_IN + kb + c * 8, (char*)sA + o);
        }
#pragma unroll
        for (int rb2 = 0; rb2 < 2; rb2++) {
            int o = rb2 * 8192 + tid * 16;
            int row = o >> 7;
            int c = ((o >> 4) & 7) ^ (row & 7);
            size_t src = (size_t)(n0 + row) * D_IN + kb + c * 8;
            gload_lds16(W1e + src, (char*)sB1 + o);
            gload_lds16(W2e + src, (char*)sB2 + o);
        }
        asm volatile("s_waitcnt vmcnt(0)" ::: "memory");
        __syncthreads();
#pragma unroll
        for (int ks = 0; ks < 2; ++ks) {
            int sb = ks * 4 + lh;
            s16x8 av[4];
#pragma unroll
            for (int mf = 0; mf < 4; ++mf) {
                int r = wm * 64 + mf * 16 + lr;
                av[mf] = *(const s16x8*)&sA[r * 64 + ((sb ^ (r & 7)) << 3)];
            }
#pragma unroll
            for (int nf = 0; nf < 2; ++nf) {
                int n = wn * 32 + nf * 16 + lr;
                int off = n * 64 + ((sb ^ (n & 7)) << 3);
                s16x8 bv1 = *(const s16x8*)&sB1[off];
                s16x8 bv2 = *(const s16x8*)&sB2[off];
#pragma unroll
                for (int mf = 0; mf < 4; ++mf) {
                    acc1[mf][nf] = __builtin_amdgcn_mfma_f32_16x16x32_bf16(av[mf], bv1, acc1[mf][nf], 0, 0, 0);
                    acc2[mf][nf] = __builtin_amdgcn_mfma_f32_16x16x32_bf16(av[mf], bv2, acc2[mf][nf], 0, 0, 0);
                }
            }
        }
        __syncthreads();
    }
#pragma unroll
    for (int mf = 0; mf < 4; ++mf) {
        int rbase = wm * 64 + mf * 16 + lh * 4;
#pragma unroll
        for (int nf = 0; nf < 2; ++nf) {
            int n = n0 + wn * 32 + nf * 16 + lr;
            float bb1 = b1[e * H_DIM + n], bb2 = b2[e * H_DIM + n];
#pragma unroll
            for (int j = 0; j < 4; ++j) {
                int r = rbase + j;
                if (r < vr) {
                    float x1 = acc1[mf][nf][j] + bb1;
                    float x2 = acc2[mf][nf][j] + bb2;
                    float h = x1 / (1.f + __expf(-x1)) * x2;
                    Hbuf[(size_t)(g0 + r) * H_DIM + n] = f2bf(h);
                }
            }
        }
    }
}

// ---- ffn2: Y = gate * (H@W3 + b3), f32 out (R8/R11 structure) ----
__global__ __launch_bounds__(256) void ffn2_kernel(
    const unsigned short* __restrict__ Hbuf, const unsigned short* __restrict__ W3T,
    const float* __restrict__ b3, const float* __restrict__ rowGate,
    float* __restrict__ Ybuf, const int* __restrict__ counts) {
    int u = xcd_swz(blockIdx.x, GRID2);
    int bx = u / (D_IN / BN2);
    int by = u - bx * (D_IN / BN2);
    int e, g0, vr;
    if (!tile_map(counts, bx, e, g0, vr)) return;
    int n0 = by * BN2;

    __shared__ __align__(16) unsigned short sA[2][BM * BK];
    __shared__ __align__(16) unsigned short sB[2][BN2 * BK];

    int tid = threadIdx.x, lane = tid & 63, w = tid >> 6;
    int wm = w >> 1, wn = w & 1;
    int lr = lane & 15, lh = lane >> 4;

    f32x4 acc[4][4];
#pragma unroll
    for (int a = 0; a < 4; a++)
#pragma unroll
        for (int b = 0; b < 4; b++) acc[a][b] = (f32x4)0.f;

    const unsigned short* W3e = W3T + (size_t)e * D_IN * H_DIM;

    auto stage = [&](int buf, int kt) {
        int kb = kt * BK;
#pragma unroll
        for (int ca = 0; ca < 4; ca++) {
            int o = ca * 4096 + tid * 16;
            int row = o >> 7;
            int c = ((o >> 4) & 7) ^ (row & 7);
            int gr = g0 + row; if (gr > NP - 1) gr = NP - 1;
            gload_lds16(Hbuf + (size_t)gr * H_DIM + kb + c * 8, (char*)&sA[buf][0] + o);
        }
#pragma unroll
        for (int cb = 0; cb < 4; cb++) {
            int o = cb * 4096 + tid * 16;
            int row = o >> 7;
            int c = ((o >> 4) & 7) ^ (row & 7);
            gload_lds16(W3e + (size_t)(n0 + row) * H_DIM + kb + c * 8, (char*)&sB[buf][0] + o);
        }
    };

    const int NKT = H_DIM / BK;
    stage(0, 0);
    stage(1, 1);
    __builtin_amdgcn_sched_barrier(0);
#pragma unroll 1
    for (int kt = 0; kt < NKT; ++kt) {
        if (kt < NKT - 1) { asm volatile("s_waitcnt vmcnt(8)" ::: "memory"); }
        else              { asm volatile("s_waitcnt vmcnt(0)" ::: "memory"); }
        __builtin_amdgcn_s_barrier();
        __builtin_amdgcn_sched_barrier(0);
        int cur = kt & 1;
#pragma unroll
        for (int ks = 0; ks < 2; ++ks) {
            int sb = ks * 4 + lh;
            s16x8 av[4], bv[4];
#pragma unroll
            for (int mf = 0; mf < 4; ++mf) {
                int r = wm * 64 + mf * 16 + lr;
                av[mf] = *(const s16x8*)&sA[cur][r * 64 + ((sb ^ (r & 7)) << 3)];
            }
#pragma unroll
            for (int nf = 0; nf < 4; ++nf) {
                int n = wn * 64 + nf * 16 + lr;
                bv[nf] = *(const s16x8*)&sB[cur][n * 64 + ((sb ^ (n & 7)) << 3)];
            }
#pragma unroll
            for (int nf = 0; nf < 4; ++nf)
#pragma unroll
                for (int mf = 0; mf < 4; ++mf)
                    acc[mf][nf] = __builtin_amdgcn_mfma_f32_16x16x32_bf16(av[mf], bv[nf], acc[mf][nf], 0, 0, 0);
        }
        __builtin_amdgcn_sched_barrier(0);
        __builtin_amdgcn_s_barrier();
        if (kt + 2 < NKT) { stage(cur, kt + 2); __builtin_amdgcn_sched_barrier(0); }
    }
#pragma unroll
    for (int mf = 0; mf < 4; ++mf) {
        int rbase = wm * 64 + mf * 16 + lh * 4;
#pragma unroll
        for (int nf = 0; nf < 4; ++nf) {
            int n = n0 + wn * 64 + nf * 16 + lr;
            float bb = b3[e * D_IN + n];
#pragma unroll
            for (int j = 0; j < 4; ++j) {
                int r = rbase + j;
                if (r < vr) {
                    float g = rowGate[g0 + r];
                    Ybuf[(size_t)(g0 + r) * D_IN + n] = g * (acc[mf][nf][j] + bb);
                }
            }
        }
    }
}

// ---- combine ----
__global__ __launch_bounds__(192) void combine_kernel(
    const float* __restrict__ Ybuf, const int* __restrict__ pairPos, float* __restrict__ out) {
    int t = blockIdx.x, i = threadIdx.x;
    int p0 = pairPos[t * 2], p1 = pairPos[t * 2 + 1];
    float4 a = ((const float4*)(Ybuf + (size_t)p0 * D_IN))[i];
    float4 b = ((const float4*)(Ybuf + (size_t)p1 * D_IN))[i];
    float4 r; r.x = a.x + b.x; r.y = a.y + b.y; r.z = a.z + b.z; r.w = a.w + b.w;
    ((float4*)(out + (size_t)t * D_IN))[i] = r;
}

extern "C" void kernel_launch(void* const* d_in, const int* in_sizes, int n_in,
                              void* d_out, int out_size, void* d_ws, size_t ws_size,
                              hipStream_t stream) {
    const float* x  = (const float*)d_in[0];
    const float* rw = (const float*)d_in[1];
    const float* rb = (const float*)d_in[2];
    const float* w1 = (const float*)d_in[3];
    const float* b1 = (const float*)d_in[4];
    const float* w2 = (const float*)d_in[5];
    const float* b2 = (const float*)d_in[6];
    const float* w3 = (const float*)d_in[7];
    const float* b3 = (const float*)d_in[8];
    float* out = (float*)d_out;

    char* ws = (char*)d_ws;
    const size_t sW = (size_t)N_EXP * H_DIM * D_IN * 2;
    unsigned short* W1T = (unsigned short*)(ws);
    unsigned short* W2T = (unsigned short*)(ws + sW);
    unsigned short* W3T = (unsigned short*)(ws + 2 * sW);
    unsigned short* Xc  = (unsigned short*)(ws + 3 * sW);
    unsigned short* Hb  = (unsigned short*)(ws + 3 * sW + (size_t)N_TOK * D_IN * 2);
    float* Yb = (float*)(ws + 3 * sW + (size_t)N_TOK * D_IN * 2 + (size_t)NP * H_DIM * 2);
    char* meta = (char*)(Yb + (size_t)NP * D_IN);
    int*   counts  = (int*)(meta + 0);
    int*   top1    = (int*)(meta + 32);
    float* psum    = (float*)(meta + 64);
    int*   cursors = (int*)(meta + 96);
    int*   tk_e    = (int*)(meta + 1024);
    float* tk_w    = (float*)(meta + 1024 + 32768);
    int*   rowTok  = (int*)(meta + 1024 + 65536);
    float* rowGate = (float*)(meta + 1024 + 98304);
    int*   pairPos = (int*)(meta + 1024 + 131072);
    size_t need = (size_t)(meta - ws) + 1024 + 163840;
    if (ws_size < need) return;

    hipMemsetAsync(meta, 0, 128, stream);
    prep2_kernel<<<PREP_ALL, 256, 0, stream>>>(
        w1, w2, w3, W1T, W2T, W3T, x, rw, rb, counts, top1, psum, tk_e, tk_w, Xc);
    scatter_kernel<<<N_TOK / 64, 64, 0, stream>>>(
        tk_e, tk_w, counts, cursors, rowTok, rowGate, pairPos,
        top1, psum, out + (size_t)N_TOK * D_IN);
    ffn1_kernel<<<GRID1, 512, 0, stream>>>(Xc, W1T, W2T, b1, b2, Hb, counts, rowTok);
    ffn2_kernel<<<GRID2, 256, 0, stream>>>(Hb, W3T, b3, rowGate, Yb, counts);
    combine_kernel<<<N_TOK, 192, 0, stream>>>(Yb, pairPos, out);
}

// Round 17
// 285.956 us; speedup vs baseline: 1.0865x; 1.0014x over previous
//
#include <hip/hip_runtime.h>
#include <hip/hip_bf16.h>
#include <math.h>

#define N_TOK 4096
#define D_IN  768
#define N_EXP 8
#define NP    8192      // N_TOK * TOPK
#define H_DIM 3072
#define BM    128
#define BK    64
#define BN1   128
#define BN2   128
#define MAXT  72
#define GRID1 (MAXT * (H_DIM / BN1))   // 1728, div by 8
#define GRID2 (MAXT * (D_IN / BN2))    // 432, div by 8
#define NT_BLKS 3456                   // 24 mats * 144 tiles (64 rows x 256 cols)
#define TPE   144
#define PREP_R (NT_BLKS + 256)         // router block range end
#define PREP_ALL (PREP_R + 1024)       // + xcvt blocks (4 tokens each)

typedef float f32x4 __attribute__((ext_vector_type(4)));
typedef short s16x8 __attribute__((ext_vector_type(8)));

__device__ __forceinline__ unsigned short f2bf(float f) {
    unsigned int u = __builtin_bit_cast(unsigned int, f);
    u += 0x7fffu + ((u >> 16) & 1u);
    return (unsigned short)(u >> 16);
}

__device__ __forceinline__ void gload_lds16(const void* g, void* l) {
    __builtin_amdgcn_global_load_lds(
        (const __attribute__((address_space(1))) unsigned int*)g,
        (__attribute__((address_space(3))) unsigned int*)l, 16, 0, 0);
}

__device__ __forceinline__ int xcd_swz(int bid, int nblk) {
    int chunk = nblk >> 3;
    return (bid & 7) * chunk + (bid >> 3);
}

__device__ __forceinline__ bool tile_map(const int* counts, int bx, int& e, int& g0, int& vr) {
    int off = 0, nt = 0;
    e = -1;
    int lb = 0, cnt = 0;
#pragma unroll
    for (int ee = 0; ee < N_EXP; ee++) {
        int c = counts[ee];
        int t = (c + BM - 1) >> 7;
        if (bx >= nt && bx < nt + t) { e = ee; lb = (bx - nt) * BM; g0 = off + lb; cnt = c; }
        nt += t; off += c;
    }
    if (e < 0) return false;
    vr = cnt - lb; if (vr > BM) vr = BM;
    return true;
}

// ---- prep2: transpose (3456) + router (256) + xcvt (1024) in ONE launch ----
__global__ __launch_bounds__(256) void prep2_kernel(
    const float* __restrict__ w1, const float* __restrict__ w2, const float* __restrict__ w3,
    unsigned short* __restrict__ W1T, unsigned short* __restrict__ W2T,
    unsigned short* __restrict__ W3T,
    const float* __restrict__ x, const float* __restrict__ rw, const float* __restrict__ rb,
    int* counts, int* top1cnt, float* probs_sum, int* tk_e, float* tk_w,
    unsigned short* __restrict__ Xc) {
    int bid = blockIdx.x, tid = threadIdx.x;

    if (bid < NT_BLKS) {
        int z = bid / TPE;
        int tt = bid - z * TPE;
        const float* s;
        unsigned short* d;
        int R, C, tc;
        if (z < 8)       { s = w1 + (size_t)z * D_IN * H_DIM;        d = W1T + (size_t)z * H_DIM * D_IN;        R = D_IN;  C = H_DIM; tc = 12; }
        else if (z < 16) { s = w2 + (size_t)(z - 8) * D_IN * H_DIM;  d = W2T + (size_t)(z - 8) * H_DIM * D_IN;  R = D_IN;  C = H_DIM; tc = 12; }
        else             { s = w3 + (size_t)(z - 16) * H_DIM * D_IN; d = W3T + (size_t)(z - 16) * D_IN * H_DIM; R = H_DIM; C = D_IN;  tc = 3;  }
        int r0 = (tt / tc) * 64, c0 = (tt % tc) * 256;
        int lane = tid & 63, w = tid >> 6;
        int tx = lane & 7, ty = lane >> 3;
        int cb = c0 + 32 * w + 4 * tx;
        int rb2 = r0 + 8 * ty;
        const float* sp  = s + (size_t)rb2 * C + cb;
        const float* sp2 = sp + 128;
        f32x4 L[8], M[8];
#pragma unroll
        for (int i = 0; i < 8; i++)
            L[i] = __builtin_nontemporal_load((const f32x4*)(sp + (size_t)i * C));
#pragma unroll
        for (int i = 0; i < 8; i++)
            M[i] = __builtin_nontemporal_load((const f32x4*)(sp2 + (size_t)i * C));
#pragma unroll
        for (int j = 0; j < 4; j++) {
            s16x8 o;
#pragma unroll
            for (int k = 0; k < 8; k++) o[k] = (short)f2bf(L[k][j]);
            *(s16x8*)&d[(size_t)(cb + j) * R + rb2] = o;
        }
#pragma unroll
        for (int j = 0; j < 4; j++) {
            s16x8 o;
#pragma unroll
            for (int k = 0; k < 8; k++) o[k] = (short)f2bf(M[k][j]);
            *(s16x8*)&d[(size_t)(cb + 128 + j) * R + rb2] = o;
        }
    } else if (bid < PREP_R) {
        __shared__ float s_ps[N_EXP];
        __shared__ int s_cnt[N_EXP], s_t1[N_EXP];
        int rbid = bid - NT_BLKS;
        if (tid < N_EXP) { s_ps[tid] = 0.f; s_cnt[tid] = 0; s_t1[tid] = 0; }
        __syncthreads();
        int tok = rbid * 16 + (tid >> 4);
        int part = tid & 15;
        float acc[N_EXP];
#pragma unroll
        for (int e = 0; e < N_EXP; e++) acc[e] = 0.f;
        const float* xr = x + (size_t)tok * D_IN + part * 48;
        const float* rwr = rw + (size_t)part * 48 * N_EXP;
        for (int dd = 0; dd < 48; dd++) {
            float xv = xr[dd];
            f32x4 ra = *(const f32x4*)(rwr + dd * N_EXP);
            f32x4 rbv = *(const f32x4*)(rwr + dd * N_EXP + 4);
            acc[0] += xv * ra[0]; acc[1] += xv * ra[1]; acc[2] += xv * ra[2]; acc[3] += xv * ra[3];
            acc[4] += xv * rbv[0]; acc[5] += xv * rbv[1]; acc[6] += xv * rbv[2]; acc[7] += xv * rbv[3];
        }
#pragma unroll
        for (int s = 1; s < 16; s <<= 1)
#pragma unroll
            for (int e = 0; e < N_EXP; e++) acc[e] += __shfl_xor(acc[e], s, 64);
        if (part == 0) {
            float p[N_EXP], m, ssum = 0.f;
#pragma unroll
            for (int e = 0; e < N_EXP; e++) acc[e] += rb[e];
            m = acc[0];
#pragma unroll
            for (int e = 1; e < N_EXP; e++) m = fmaxf(m, acc[e]);
#pragma unroll
            for (int e = 0; e < N_EXP; e++) { p[e] = __expf(acc[e] - m); ssum += p[e]; }
            float inv = 1.f / ssum;
#pragma unroll
            for (int e = 0; e < N_EXP; e++) p[e] *= inv;
            int e0 = 0;
#pragma unroll
            for (int e = 1; e < N_EXP; e++) if (p[e] > p[e0]) e0 = e;
            int e1 = (e0 == 0) ? 1 : 0;
#pragma unroll
            for (int e = 0; e < N_EXP; e++) if (e != e0 && p[e] > p[e1]) e1 = e;
            float denom = 1.f / (p[e0] + p[e1]);
            tk_e[tok * 2] = e0; tk_e[tok * 2 + 1] = e1;
            tk_w[tok * 2] = p[e0] * denom; tk_w[tok * 2 + 1] = p[e1] * denom;
            atomicAdd(&s_cnt[e0], 1); atomicAdd(&s_cnt[e1], 1); atomicAdd(&s_t1[e0], 1);
#pragma unroll
            for (int e = 0; e < N_EXP; e++) atomicAdd(&s_ps[e], p[e]);
        }
        __syncthreads();
        if (tid < N_EXP) {
            atomicAdd(&counts[tid], s_cnt[tid]);
            atomicAdd(&top1cnt[tid], s_t1[tid]);
            atomicAdd(&probs_sum[tid], s_ps[tid]);
        }
    } else {
        int cb = bid - PREP_R;
        size_t base = (size_t)cb * 768;   // in float4 units
#pragma unroll
        for (int it = 0; it < 3; it++) {
            size_t idx = base + tid + it * 256;
            float4 v = ((const float4*)x)[idx];
            unsigned long long pk = (unsigned long long)f2bf(v.x)
                                  | ((unsigned long long)f2bf(v.y) << 16)
                                  | ((unsigned long long)f2bf(v.z) << 32)
                                  | ((unsigned long long)f2bf(v.w) << 48);
            ((unsigned long long*)Xc)[idx] = pk;
        }
    }
}

// ---- scatter ----
__global__ __launch_bounds__(64) void scatter_kernel(
    const int* __restrict__ tk_e, const float* __restrict__ tk_w,
    const int* __restrict__ counts, int* cursors,
    int* rowTok, float* rowGate, int* pairPos,
    const int* __restrict__ top1cnt, const float* __restrict__ probs_sum, float* aux_out) {
    int tid = threadIdx.x;
    int tok = blockIdx.x * 64 + tid;
    int segOff[N_EXP];
    int off = 0;
#pragma unroll
    for (int e = 0; e < N_EXP; e++) { segOff[e] = off; off += counts[e]; }
#pragma unroll
    for (int k = 0; k < 2; k++) {
        int e = tk_e[tok * 2 + k];
        int pos = segOff[e] + atomicAdd(&cursors[e], 1);
        rowTok[pos] = tok;
        rowGate[pos] = tk_w[tok * 2 + k];
        pairPos[tok * 2 + k] = pos;
    }
    if (blockIdx.x == 0 && tid == 0) {
        float aux = 0.f;
#pragma unroll
        for (int e = 0; e < N_EXP; e++) aux += (float)top1cnt[e] * probs_sum[e];
        aux_out[0] = (float)N_EXP * aux / ((float)N_TOK * (float)N_TOK);
    }
}

// ---- ffn1: H = silu(X@W1+b1) * (X@W2+b2), bf16 out (R13 structure) ----
// by-major XCD decode: 72 consecutive co-XCD blocks share one W-panel (L2 reuse).
__global__ __launch_bounds__(512) void ffn1_kernel(
    const unsigned short* __restrict__ Xc, const unsigned short* __restrict__ W1T,
    const unsigned short* __restrict__ W2T, const float* __restrict__ b1,
    const float* __restrict__ b2, unsigned short* __restrict__ Hbuf,
    const int* __restrict__ counts, const int* __restrict__ rowTok) {
    int u = xcd_swz(blockIdx.x, GRID1);
    int by = u / MAXT;          // W-panel index (24), slow within XCD chunk
    int bx = u - by * MAXT;     // M-tile index (72), fast
    int e, g0, vr;
    if (!tile_map(counts, bx, e, g0, vr)) return;
    int n0 = by * BN1;

    __shared__ __align__(16) unsigned short sA[BM * BK];
    __shared__ __align__(16) unsigned short sB1[BN1 * BK];
    __shared__ __align__(16) unsigned short sB2[BN1 * BK];

    int tid = threadIdx.x, lane = tid & 63, w = tid >> 6;
    int wm = w >> 2, wn = w & 3;
    int lr = lane & 15, lh = lane >> 4;

    int tokA[2];
#pragma unroll
    for (int ra = 0; ra < 2; ra++) {
        int row = (ra * 8192 + tid * 16) >> 7;
        int gi = g0 + row; if (gi > NP - 1) gi = NP - 1;
        tokA[ra] = rowTok[gi];
    }

    f32x4 acc1[4][2], acc2[4][2];
#pragma unroll
    for (int a = 0; a < 4; a++)
#pragma unroll
        for (int b = 0; b < 2; b++) { acc1[a][b] = (f32x4)0.f; acc2[a][b] = (f32x4)0.f; }

    const unsigned short* W1e = W1T + (size_t)e * H_DIM * D_IN;
    const unsigned short* W2e = W2T + (size_t)e * H_DIM * D_IN;

    for (int kt = 0; kt < D_IN / BK; ++kt) {
        int kb = kt * BK;
#pragma unroll
        for (int ra = 0; ra < 2; ra++) {
            int o = ra * 8192 + tid * 16;
            int row = o >> 7;
            int c = ((o >> 4) & 7) ^ (row & 7);
            gload_lds16(Xc + (size_t)tokA[ra] * D_IN + kb + c * 8, (char*)sA + o);
        }
#pragma unroll
        for (int rb2 = 0; rb2 < 2; rb2++) {
            int o = rb2 * 8192 + tid * 16;
            int row = o >> 7;
            int c = ((o >> 4) & 7) ^ (row & 7);
            size_t src = (size_t)(n0 + row) * D_IN + kb + c * 8;
            gload_lds16(W1e + src, (char*)sB1 + o);
            gload_lds16(W2e + src, (char*)sB2 + o);
        }
        asm volatile("s_waitcnt vmcnt(0)" ::: "memory");
        __syncthreads();
#pragma unroll
        for (int ks = 0; ks < 2; ++ks) {
            int sb = ks * 4 + lh;
            s16x8 av[4];
#pragma unroll
            for (int mf = 0; mf < 4; ++mf) {
                int r = wm * 64 + mf * 16 + lr;
                av[mf] = *(const s16x8*)&sA[r * 64 + ((sb ^ (r & 7)) << 3)];
            }
#pragma unroll
            for (int nf = 0; nf < 2; ++nf) {
                int n = wn * 32 + nf * 16 + lr;
                int off = n * 64 + ((sb ^ (n & 7)) << 3);
                s16x8 bv1 = *(const s16x8*)&sB1[off];
                s16x8 bv2 = *(const s16x8*)&sB2[off];
#pragma unroll
                for (int mf = 0; mf < 4; ++mf) {
                    acc1[mf][nf] = __builtin_amdgcn_mfma_f32_16x16x32_bf16(av[mf], bv1, acc1[mf][nf], 0, 0, 0);
                    acc2[mf][nf] = __builtin_amdgcn_mfma_f32_16x16x32_bf16(av[mf], bv2, acc2[mf][nf], 0, 0, 0);
                }
            }
        }
        __syncthreads();
    }
#pragma unroll
    for (int mf = 0; mf < 4; ++mf) {
        int rbase = wm * 64 + mf * 16 + lh * 4;
#pragma unroll
        for (int nf = 0; nf < 2; ++nf) {
            int n = n0 + wn * 32 + nf * 16 + lr;
            float bb1 = b1[e * H_DIM + n], bb2 = b2[e * H_DIM + n];
#pragma unroll
            for (int j = 0; j < 4; ++j) {
                int r = rbase + j;
                if (r < vr) {
                    float x1 = acc1[mf][nf][j] + bb1;
                    float x2 = acc2[mf][nf][j] + bb2;
                    float h = x1 / (1.f + __expf(-x1)) * x2;
                    Hbuf[(size_t)(g0 + r) * H_DIM + n] = f2bf(h);
                }
            }
        }
    }
}

// ---- ffn2: Y = gate * (H@W3 + b3), f32 out (R8/R11 structure) ----
__global__ __launch_bounds__(256) void ffn2_kernel(
    const unsigned short* __restrict__ Hbuf, const unsigned short* __restrict__ W3T,
    const float* __restrict__ b3, const float* __restrict__ rowGate,
    float* __restrict__ Ybuf, const int* __restrict__ counts) {
    int u = xcd_swz(blockIdx.x, GRID2);
    int bx = u / (D_IN / BN2);
    int by = u - bx * (D_IN / BN2);
    int e, g0, vr;
    if (!tile_map(counts, bx, e, g0, vr)) return;
    int n0 = by * BN2;

    __shared__ __align__(16) unsigned short sA[2][BM * BK];
    __shared__ __align__(16) unsigned short sB[2][BN2 * BK];

    int tid = threadIdx.x, lane = tid & 63, w = tid >> 6;
    int wm = w >> 1, wn = w & 1;
    int lr = lane & 15, lh = lane >> 4;

    f32x4 acc[4][4];
#pragma unroll
    for (int a = 0; a < 4; a++)
#pragma unroll
        for (int b = 0; b < 4; b++) acc[a][b] = (f32x4)0.f;

    const unsigned short* W3e = W3T + (size_t)e * D_IN * H_DIM;

    auto stage = [&](int buf, int kt) {
        int kb = kt * BK;
#pragma unroll
        for (int ca = 0; ca < 4; ca++) {
            int o = ca * 4096 + tid * 16;
            int row = o >> 7;
            int c = ((o >> 4) & 7) ^ (row & 7);
            int gr = g0 + row; if (gr > NP - 1) gr = NP - 1;
            gload_lds16(Hbuf + (size_t)gr * H_DIM + kb + c * 8, (char*)&sA[buf][0] + o);
        }
#pragma unroll
        for (int cb = 0; cb < 4; cb++) {
            int o = cb * 4096 + tid * 16;
            int row = o >> 7;
            int c = ((o >> 4) & 7) ^ (row & 7);
            gload_lds16(W3e + (size_t)(n0 + row) * H_DIM + kb + c * 8, (char*)&sB[buf][0] + o);
        }
    };

    const int NKT = H_DIM / BK;
    stage(0, 0);
    stage(1, 1);
    __builtin_amdgcn_sched_barrier(0);
#pragma unroll 1
    for (int kt = 0; kt < NKT; ++kt) {
        if (kt < NKT - 1) { asm volatile("s_waitcnt vmcnt(8)" ::: "memory"); }
        else              { asm volatile("s_waitcnt vmcnt(0)" ::: "memory"); }
        __builtin_amdgcn_s_barrier();
        __builtin_amdgcn_sched_barrier(0);
        int cur = kt & 1;
#pragma unroll
        for (int ks = 0; ks < 2; ++ks) {
            int sb = ks * 4 + lh;
            s16x8 av[4], bv[4];
#pragma unroll
            for (int mf = 0; mf < 4; ++mf) {
                int r = wm * 64 + mf * 16 + lr;
                av[mf] = *(const s16x8*)&sA[cur][r * 64 + ((sb ^ (r & 7)) << 3)];
            }
#pragma unroll
            for (int nf = 0; nf < 4; ++nf) {
                int n = wn * 64 + nf * 16 + lr;
                bv[nf] = *(const s16x8*)&sB[cur][n * 64 + ((sb ^ (n & 7)) << 3)];
            }
#pragma unroll
            for (int nf = 0; nf < 4; ++nf)
#pragma unroll
                for (int mf = 0; mf < 4; ++mf)
                    acc[mf][nf] = __builtin_amdgcn_mfma_f32_16x16x32_bf16(av[mf], bv[nf], acc[mf][nf], 0, 0, 0);
        }
        __builtin_amdgcn_sched_barrier(0);
        __builtin_amdgcn_s_barrier();
        if (kt + 2 < NKT) { stage(cur, kt + 2); __builtin_amdgcn_sched_barrier(0); }
    }
#pragma unroll
    for (int mf = 0; mf < 4; ++mf) {
        int rbase = wm * 64 + mf * 16 + lh * 4;
#pragma unroll
        for (int nf = 0; nf < 4; ++nf) {
            int n = n0 + wn * 64 + nf * 16 + lr;
            float bb = b3[e * D_IN + n];
#pragma unroll
            for (int j = 0; j < 4; ++j) {
                int r = rbase + j;
                if (r < vr) {
                    float g = rowGate[g0 + r];
                    Ybuf[(size_t)(g0 + r) * D_IN + n] = g * (acc[mf][nf][j] + bb);
                }
            }
        }
    }
}

// ---- combine ----
__global__ __launch_bounds__(192) void combine_kernel(
    const float* __restrict__ Ybuf, const int* __restrict__ pairPos, float* __restrict__ out) {
    int t = blockIdx.x, i = threadIdx.x;
    int p0 = pairPos[t * 2], p1 = pairPos[t * 2 + 1];
    float4 a = ((const float4*)(Ybuf + (size_t)p0 * D_IN))[i];
    float4 b = ((const float4*)(Ybuf + (size_t)p1 * D_IN))[i];
    float4 r; r.x = a.x + b.x; r.y = a.y + b.y; r.z = a.z + b.z; r.w = a.w + b.w;
    ((float4*)(out + (size_t)t * D_IN))[i] = r;
}

extern "C" void kernel_launch(void* const* d_in, const int* in_sizes, int n_in,
                              void* d_out, int out_size, void* d_ws, size_t ws_size,
                              hipStream_t stream) {
    const float* x  = (const float*)d_in[0];
    const float* rw = (const float*)d_in[1];
    const float* rb = (const float*)d_in[2];
    const float* w1 = (const float*)d_in[3];
    const float* b1 = (const float*)d_in[4];
    const float* w2 = (const float*)d_in[5];
    const float* b2 = (const float*)d_in[6];
    const float* w3 = (const float*)d_in[7];
    const float* b3 = (const float*)d_in[8];
    float* out = (float*)d_out;

    char* ws = (char*)d_ws;
    const size_t sW = (size_t)N_EXP * H_DIM * D_IN * 2;
    unsigned short* W1T = (unsigned short*)(ws);
    unsigned short* W2T = (unsigned short*)(ws + sW);
    unsigned short* W3T = (unsigned short*)(ws + 2 * sW);
    unsigned short* Xc  = (unsigned short*)(ws + 3 * sW);
    unsigned short* Hb  = (unsigned short*)(ws + 3 * sW + (size_t)N_TOK * D_IN * 2);
    float* Yb = (float*)(ws + 3 * sW + (size_t)N_TOK * D_IN * 2 + (size_t)NP * H_DIM * 2);
    char* meta = (char*)(Yb + (size_t)NP * D_IN);
    int*   counts  = (int*)(meta + 0);
    int*   top1    = (int*)(meta + 32);
    float* psum    = (float*)(meta + 64);
    int*   cursors = (int*)(meta + 96);
    int*   tk_e    = (int*)(meta + 1024);
    float* tk_w    = (float*)(meta + 1024 + 32768);
    int*   rowTok  = (int*)(meta + 1024 + 65536);
    float* rowGate = (float*)(meta + 1024 + 98304);
    int*   pairPos = (int*)(meta + 1024 + 131072);
    size_t need = (size_t)(meta - ws) + 1024 + 163840;
    if (ws_size < need) return;

    hipMemsetAsync(meta, 0, 128, stream);
    prep2_kernel<<<PREP_ALL, 256, 0, stream>>>(
        w1, w2, w3, W1T, W2T, W3T, x, rw, rb, counts, top1, psum, tk_e, tk_w, Xc);
    scatter_kernel<<<N_TOK / 64, 64, 0, stream>>>(
        tk_e, tk_w, counts, cursors, rowTok, rowGate, pairPos,
        top1, psum, out + (size_t)N_TOK * D_IN);
    ffn1_kernel<<<GRID1, 512, 0, stream>>>(Xc, W1T, W2T, b1, b2, Hb, counts, rowTok);
    ffn2_kernel<<<GRID2, 256, 0, stream>>>(Hb, W3T, b3, rowGate, Yb, counts);
    combine_kernel<<<N_TOK, 192, 0, stream>>>(Yb, pairPos, out);
}